// Round 9
// baseline (1464.079 us; speedup 1.0000x reference)
//
#include <hip/hip_runtime.h>
#include <math.h>

#define NPTS 576
#define N2 331776           // 576*576
#define BSZ 4
#define NB 64               // cholesky block
#define NT 9                // 576/64

#define INVL2 (1.0f/0.29311396f)

// ---------------------------------------------------------------------------
__global__ void copy_xout(const float* __restrict__ xin, float* __restrict__ out) {
    int idx = blockIdx.x * 256 + threadIdx.x;   // 18*256 = 4608 exact
    out[idx] = xin[idx];
}

// ---------------------------------------------------------------------------
// build Kxx (+jitter) and opiK (4 planes) from xin
// ---------------------------------------------------------------------------
__global__ void build_k(const float* __restrict__ xin,
                        float* __restrict__ Kxx, float* __restrict__ opiK) {
    int idx = blockIdx.x * 256 + threadIdx.x;
    int b = idx / N2;
    int rem = idx - b * N2;
    int m = rem / NPTS;
    int nn = rem - m * NPTS;
    const float* xb = xin + (size_t)b * NPTS * 2;
    float xm0 = xb[m*2],  xm1 = xb[m*2+1];
    float xn0 = xb[nn*2], xn1 = xb[nn*2+1];
    float r0 = xm0 - xn0, r1 = xm1 - xn1;
    float u = (r0*r0 + r1*r1) * INVL2;
    float Kv = expf(-0.5f * u);
    Kxx[idx] = Kv + ((m == nn) ? 1e-5f : 0.0f);
    size_t base = (size_t)b * 4 * N2 + rem;
    opiK[base]          = Kv;
    opiK[base + N2]     = -r0 * INVL2 * Kv;
    opiK[base + 2*N2]   = -r1 * INVL2 * Kv;
    opiK[base + 3*N2]   = (u - 2.0f) * INVL2 * Kv;
}

// ---------------------------------------------------------------------------
__global__ void w2_k(const float* __restrict__ w, float* __restrict__ W2) {
    __shared__ float red[256];
    int tid = threadIdx.x;
    int pair = tid & 15;
    int slice = tid >> 4;
    int i = pair >> 2, j = pair & 3;
    float s = 0.0f;
    for (int o = slice * 4; o < slice * 4 + 4; ++o)
        for (int c = 0; c < 32; ++c)
            s += w[o*128 + c*4 + i] * w[o*128 + c*4 + j];
    red[tid] = s;
    __syncthreads();
    if (tid < 16) {
        float t = 0.0f;
        #pragma unroll
        for (int k = 0; k < 16; ++k) t += red[pair + 16*k];
        W2[pair] = t * (1.0f/64.0f);
    }
}

// ---------------------------------------------------------------------------
// factor 64x64 SPD block in T (lower), produce V = T^{-1} (lower).
// Panel-blocked: in-wave 16-col panel factor + 16-rank SYRK per panel.
// ---------------------------------------------------------------------------
__device__ void factor_invert_64(float (*T)[NB+1], float (*V)[NB+1],
                                 float (*tmp)[17], int tid) {
    for (int p = 0; p < 4; ++p) {
        int cp = p * 16;
        if (tid < 64) {
            int r = tid;
            #pragma unroll 1
            for (int j = 0; j < 16; ++j) {
                int col = cp + j;
                if (r == col) T[col][col] = sqrtf(fmaxf(T[col][col], 1e-12f));
                float d = T[col][col];
                float lr = 0.0f;
                if (r > col) { lr = T[r][col] / d; T[r][col] = lr; }
                #pragma unroll 1
                for (int c = col + 1; c < cp + 16; ++c) {
                    float lc = T[c][col];
                    if (r >= c) T[r][c] -= lr * lc;
                }
            }
        }
        __syncthreads();
        int tr = 48 - cp;
        if (tr > 0) {
            for (int idx = tid; idx < tr * tr; idx += 256) {
                int r = cp + 16 + idx / tr;
                int c = cp + 16 + idx % tr;
                if (c <= r) {
                    float s = 0.0f;
                    #pragma unroll
                    for (int k = 0; k < 16; ++k) s += T[r][cp+k] * T[c][cp+k];
                    T[r][c] -= s;
                }
            }
        }
        __syncthreads();
    }
    if (tid < 64) {
        int I = tid >> 4, c = tid & 15, base = I * 16;
        for (int i = c; i < 16; ++i) {
            float s = (i == c) ? 1.0f : 0.0f;
            for (int k = c; k < i; ++k) s -= T[base+i][base+k] * V[base+k][base+c];
            V[base+i][base+c] = s / T[base+i][base+i];
        }
    }
    __syncthreads();
    const int PI[6] = {1,2,3,2,3,3};
    const int PJ[6] = {0,1,2,0,1,0};
    int rr16 = tid >> 4, cc16 = tid & 15;
    for (int p = 0; p < 6; ++p) {
        int I = PI[p], J = PJ[p];
        float s = 0.0f;
        for (int K = J; K < I; ++K)
            #pragma unroll
            for (int t = 0; t < 16; ++t)
                s += T[I*16+rr16][K*16+t] * V[K*16+t][J*16+cc16];
        tmp[rr16][cc16] = s;
        __syncthreads();
        float s2 = 0.0f;
        for (int t = 0; t <= rr16; ++t) s2 += V[I*16+rr16][I*16+t] * tmp[t][cc16];
        __syncthreads();
        V[I*16+rr16][J*16+cc16] = -s2;
        __syncthreads();
    }
}

// ---------------------------------------------------------------------------
__global__ void chol_diag0(const float* __restrict__ A, float* __restrict__ LinvKK) {
    int b = blockIdx.x;
    const float* Ab = A + (size_t)b * N2;
    __shared__ float T[NB][NB+1];
    __shared__ float V[NB][NB+1];
    __shared__ float tmp[16][17];
    int tid = threadIdx.x;
    for (int idx = tid; idx < NB*NB; idx += 256) {
        int r = idx >> 6, c = idx & 63;
        T[r][c] = Ab[(size_t)r * NPTS + c];
        V[r][c] = 0.0f;
    }
    __syncthreads();
    factor_invert_64(T, V, tmp, tid);
    float* Vg = LinvKK + (size_t)b * NT * NB * NB;
    for (int idx = tid; idx < NB*NB; idx += 256) Vg[idx] = V[idx >> 6][idx & 63];
}

// ---------------------------------------------------------------------------
// fused Cholesky step for panel kb. 9 total launches.
// ---------------------------------------------------------------------------
__global__ __launch_bounds__(256)
void chol_step(float* __restrict__ A, float* __restrict__ LL,
               float* __restrict__ LinvKK, int kb) {
    int b = blockIdx.y;
    int p = blockIdx.x;
    int ir = 0;
    while (p >= ir + 1) { p -= ir + 1; ir++; }
    int ib = kb + 1 + ir, jb = kb + 1 + p;
    float* Ab = A + (size_t)b * N2;
    float* LLb = LL + (size_t)b * N2;
    __shared__ float Ai[NB][NB+1];
    __shared__ float Aj[NB][NB+1];
    __shared__ float Vs[NB][NB+1];
    __shared__ float tmp[16][17];
    int tid = threadIdx.x;
    int tx = tid & 15, ty = tid >> 4;
    const float* Vg = LinvKK + ((size_t)b * NT + kb) * NB * NB;
    bool diag = (ib == jb);
    for (int idx = tid; idx < NB*NB; idx += 256) {
        int r = idx >> 6, c = idx & 63;
        Ai[r][c] = Ab[(size_t)(ib*NB + r) * NPTS + kb*NB + c];
        Aj[r][c] = diag ? 0.0f : Ab[(size_t)(jb*NB + r) * NPTS + kb*NB + c];
        Vs[r][c] = Vg[idx];
    }
    float U[4][4];
    #pragma unroll
    for (int i = 0; i < 4; ++i)
        #pragma unroll
        for (int j = 0; j < 4; ++j)
            U[i][j] = Ab[(size_t)(ib*NB + ty*4+i) * NPTS + jb*NB + tx*4+j];
    __syncthreads();
    float Li[4][4] = {}, Lj[4][4] = {};
    for (int k = 0; k < NB; ++k) {
        float a[4], v[4];
        #pragma unroll
        for (int i = 0; i < 4; ++i) a[i] = Ai[ty*4+i][k];
        #pragma unroll
        for (int j = 0; j < 4; ++j) v[j] = Vs[tx*4+j][k];
        #pragma unroll
        for (int i = 0; i < 4; ++i)
            #pragma unroll
            for (int j = 0; j < 4; ++j) Li[i][j] += a[i] * v[j];
        if (!diag) {
            float aj[4];
            #pragma unroll
            for (int i = 0; i < 4; ++i) aj[i] = Aj[ty*4+i][k];
            #pragma unroll
            for (int i = 0; i < 4; ++i)
                #pragma unroll
                for (int j = 0; j < 4; ++j) Lj[i][j] += aj[i] * v[j];
        }
    }
    __syncthreads();
    #pragma unroll
    for (int i = 0; i < 4; ++i)
        #pragma unroll
        for (int j = 0; j < 4; ++j) {
            Ai[ty*4+i][tx*4+j] = Li[i][j];
            Aj[ty*4+i][tx*4+j] = diag ? Li[i][j] : Lj[i][j];
        }
    if (diag) {
        #pragma unroll
        for (int i = 0; i < 4; ++i)
            #pragma unroll
            for (int j = 0; j < 4; ++j)
                LLb[(size_t)(ib*NB + ty*4+i) * NPTS + kb*NB + tx*4+j] = Li[i][j];
    }
    __syncthreads();
    float s[4][4] = {};
    for (int k = 0; k < NB; ++k) {
        float a[4], v[4];
        #pragma unroll
        for (int i = 0; i < 4; ++i) a[i] = Ai[ty*4+i][k];
        #pragma unroll
        for (int j = 0; j < 4; ++j) v[j] = Aj[tx*4+j][k];
        #pragma unroll
        for (int i = 0; i < 4; ++i)
            #pragma unroll
            for (int j = 0; j < 4; ++j) s[i][j] += a[i] * v[j];
    }
    #pragma unroll
    for (int i = 0; i < 4; ++i)
        #pragma unroll
        for (int j = 0; j < 4; ++j) U[i][j] -= s[i][j];
    if (blockIdx.x != 0) {
        #pragma unroll
        for (int i = 0; i < 4; ++i)
            #pragma unroll
            for (int j = 0; j < 4; ++j)
                Ab[(size_t)(ib*NB + ty*4+i) * NPTS + jb*NB + tx*4+j] = U[i][j];
        return;
    }
    __syncthreads();
    #pragma unroll
    for (int i = 0; i < 4; ++i)
        #pragma unroll
        for (int j = 0; j < 4; ++j) Ai[ty*4+i][tx*4+j] = U[i][j];
    for (int idx = tid; idx < NB*NB; idx += 256) Aj[idx >> 6][idx & 63] = 0.0f;
    __syncthreads();
    factor_invert_64(Ai, Aj, tmp, tid);
    float* Vo = LinvKK + ((size_t)b * NT + (kb + 1)) * NB * NB;
    for (int idx = tid; idx < NB*NB; idx += 256) Vo[idx] = Aj[idx >> 6][idx & 63];
}

// ---------------------------------------------------------------------------
// blocked triangular inverse. grid (4 col-splits, 9 block-cols, 4 batch)
// ---------------------------------------------------------------------------
__global__ __launch_bounds__(256)
void trinv_blk(const float* __restrict__ L, const float* __restrict__ LinvKK,
               float* __restrict__ Linv) {
    int sp = blockIdx.x, jb = blockIdx.y, b = blockIdx.z;
    const float* Lb = L + (size_t)b * N2;
    float* Xg = Linv + (size_t)b * N2;
    const float* Vg = LinvKK + (size_t)b * NT * NB * NB;
    int c0 = jb * NB + sp * 16;

    __shared__ float LsT[64][72];
    __shared__ float Xc[576][17];
    __shared__ float Ss[64][17];

    int tid = threadIdx.x;
    int tx = tid & 15, ty = tid >> 4;

    {
        const float* Vjj = Vg + (size_t)jb * NB * NB;
        int r = tid >> 2, c4 = (tid & 3) * 4;
        float4 v = *(const float4*)(Vjj + r * NB + sp * 16 + c4);
        Xc[r][c4+0] = v.x; Xc[r][c4+1] = v.y; Xc[r][c4+2] = v.z; Xc[r][c4+3] = v.w;
        *(float4*)(Xg + (size_t)(jb * NB + r) * NPTS + c0 + c4) = v;
    }
    __syncthreads();

    for (int ib = jb + 1; ib < NT; ++ib) {
        float acc[4] = {};
        for (int kb = jb; kb < ib; ++kb) {
            {
                int r = tid >> 2, t0 = (tid & 3) * 16;
                const float* src = Lb + (size_t)(ib * NB + r) * NPTS + kb * NB + t0;
                #pragma unroll
                for (int q = 0; q < 4; ++q) {
                    float4 v = *(const float4*)(src + q * 4);
                    LsT[t0 + q*4 + 0][r] = v.x;
                    LsT[t0 + q*4 + 1][r] = v.y;
                    LsT[t0 + q*4 + 2][r] = v.z;
                    LsT[t0 + q*4 + 3][r] = v.w;
                }
            }
            __syncthreads();
            int xbase = (kb - jb) * 64;
            #pragma unroll 8
            for (int t = 0; t < 64; ++t) {
                float a4[4]; *(float4*)a4 = *(const float4*)&LsT[t][ty*4];
                float xv = Xc[xbase + t][tx];
                #pragma unroll
                for (int i = 0; i < 4; ++i) acc[i] += a4[i] * xv;
            }
            __syncthreads();
        }
        #pragma unroll
        for (int i = 0; i < 4; ++i) Ss[ty*4+i][tx] = acc[i];
        {
            const float* Vii = Vg + (size_t)ib * NB * NB;
            int r = tid >> 2, t0 = (tid & 3) * 16;
            #pragma unroll
            for (int q = 0; q < 4; ++q) {
                float4 v = *(const float4*)(Vii + r * NB + t0 + q * 4);
                LsT[t0 + q*4 + 0][r] = v.x;
                LsT[t0 + q*4 + 1][r] = v.y;
                LsT[t0 + q*4 + 2][r] = v.z;
                LsT[t0 + q*4 + 3][r] = v.w;
            }
        }
        __syncthreads();
        float acc2[4] = {};
        #pragma unroll 8
        for (int t = 0; t < 64; ++t) {
            float a4[4]; *(float4*)a4 = *(const float4*)&LsT[t][ty*4];
            float sv = Ss[t][tx];
            #pragma unroll
            for (int i = 0; i < 4; ++i) acc2[i] += a4[i] * sv;
        }
        int obase = (ib - jb) * 64;
        #pragma unroll
        for (int i = 0; i < 4; ++i) {
            float v = -acc2[i];
            Xc[obase + ty*4 + i][tx] = v;
            Xg[(size_t)(ib * NB + ty*4 + i) * NPTS + c0 + tx] = v;
        }
        __syncthreads();
    }
}

// ---------------------------------------------------------------------------
// 1-WAVE GEMM: 64 threads, 64x64 C-tile, 8x8 micro-tile. XCD-swizzled 1-D
// grid. All dims assumed multiples of 64 (true here). TB=1: C = A B^T.
// SK-way K-split. EPIB=1: B := B - I during load (TB=0 only).
// C addressing: base + b*sC + sp*sSplit  (sC = batch stride, sSplit = split
// stride — MUST be distinct planes; R8's bug was sC==sSplit collision).
// ---------------------------------------------------------------------------
template<int TB, int SK, int EPIB>
__global__ __launch_bounds__(64)
void mm64(const float* __restrict__ Aall, const float* __restrict__ Ball,
          float* __restrict__ Call,
          int K, int planeK, int lda, int ldb, int ldc,
          long sA, long sB, long sC, long pA, long pB, long sSplit, int MT)
{
    int id = blockIdx.x;
    int x8 = id & 7, qq = id >> 3;
    int nx = qq % 9;
    int band = x8 + 8 * (qq / 9);
    if (band >= MT * BSZ * SK) return;
    int my = band % MT;
    int zz = band / MT;
    int sp = (SK > 1) ? (zz % SK) : 0;
    int b  = (SK > 1) ? (zz / SK) : zz;
    const float* A = Aall + (size_t)b * sA;
    const float* B = Ball + (size_t)b * sB;
    float* C = Call + (size_t)b * sC + (size_t)sp * sSplit;
    int n0 = nx * 64, m0 = my * 64;

    __shared__ float As[16][76];
    __shared__ float Bs[16][76];

    int tid = threadIdx.x;
    int tx = tid & 7, ty = tid >> 3;
    int r16 = tid >> 2, c4 = (tid & 3) * 4;

    float acc[8][8] = {};

    int kBeg = 0, kEnd = K;
    if (SK > 1) {
        int chunk = ((K / SK) + 15) & ~15;
        kBeg = sp * chunk;
        if (kBeg > K) kBeg = K;
        kEnd = (sp == SK - 1) ? K : (kBeg + chunk < K ? kBeg + chunk : K);
    }

    float ap[4][4], bp[4][4];

    auto loadA = [&](int k0) {
        int plane = k0 / planeK;
        int koff  = k0 - plane * planeK;
        const float* Ab = A + (size_t)pA * plane + (size_t)m0 * lda + koff + c4;
        #pragma unroll
        for (int p = 0; p < 4; ++p) {
            float4 t = *(const float4*)(Ab + (size_t)(r16 + p*16) * lda);
            ap[p][0]=t.x; ap[p][1]=t.y; ap[p][2]=t.z; ap[p][3]=t.w;
        }
    };
    auto storeA = [&]() {
        #pragma unroll
        for (int p = 0; p < 4; ++p)
            #pragma unroll
            for (int q = 0; q < 4; ++q)
                As[c4+q][r16 + p*16] = ap[p][q];
    };
    auto loadB = [&](int k0) {
        int plane = k0 / planeK;
        int koff  = k0 - plane * planeK;
        if (TB == 0) {
            const float* p0 = B + (size_t)(koff + r16) * ldb + n0;
            #pragma unroll
            for (int p = 0; p < 4; ++p) {
                float4 t = *(const float4*)(p0 + c4 + p*16);
                bp[p][0]=t.x; bp[p][1]=t.y; bp[p][2]=t.z; bp[p][3]=t.w;
                if (EPIB) {
                    int gk = koff + r16;
                    #pragma unroll
                    for (int jj = 0; jj < 4; ++jj)
                        if (gk == n0 + c4 + p*16 + jj) bp[p][jj] -= 1.0f;
                }
            }
        } else {
            const float* Bb = B + (size_t)pB * plane + koff + c4;
            #pragma unroll
            for (int p = 0; p < 4; ++p) {
                float4 t = *(const float4*)(Bb + (size_t)(n0 + r16 + p*16) * ldb);
                bp[p][0]=t.x; bp[p][1]=t.y; bp[p][2]=t.z; bp[p][3]=t.w;
            }
        }
    };
    auto storeB = [&]() {
        if (TB == 0) {
            #pragma unroll
            for (int p = 0; p < 4; ++p)
                *(float4*)&Bs[r16][c4 + p*16] = *(float4*)bp[p];
        } else {
            #pragma unroll
            for (int p = 0; p < 4; ++p)
                #pragma unroll
                for (int q = 0; q < 4; ++q)
                    Bs[c4+q][r16 + p*16] = bp[p][q];
        }
    };

    if (kBeg < kEnd) {
        loadA(kBeg); loadB(kBeg);
        for (int k0 = kBeg; k0 < kEnd; k0 += 16) {
            storeA(); storeB();
            __syncthreads();
            if (k0 + 16 < kEnd) { loadA(k0 + 16); loadB(k0 + 16); }
            #pragma unroll
            for (int kk = 0; kk < 16; ++kk) {
                float a[8], bb[8];
                *(float4*)a      = *(const float4*)&As[kk][ty*8];
                *(float4*)(a+4)  = *(const float4*)&As[kk][ty*8+4];
                *(float4*)bb     = *(const float4*)&Bs[kk][tx*8];
                *(float4*)(bb+4) = *(const float4*)&Bs[kk][tx*8+4];
                #pragma unroll
                for (int i = 0; i < 8; ++i)
                    #pragma unroll
                    for (int j = 0; j < 8; ++j)
                        acc[i][j] += a[i] * bb[j];
            }
            __syncthreads();
        }
    }

    #pragma unroll
    for (int i = 0; i < 8; ++i) {
        float* Cr = C + (size_t)(m0 + ty*8 + i) * ldc + n0 + tx*8;
        float4 v0, v1;
        v0.x=acc[i][0]; v0.y=acc[i][1]; v0.z=acc[i][2]; v0.w=acc[i][3];
        v1.x=acc[i][4]; v1.y=acc[i][5]; v1.z=acc[i][6]; v1.w=acc[i][7];
        *(float4*)Cr = v0;
        *(float4*)(Cr + 4) = v1;
    }
}

// ---------------------------------------------------------------------------
// batched tiled matmul, 64x64 C-tile, 256 threads (4x4 micro) — used for the
// cold/odd-shaped GEMMs. TA=1: C=A^T B. SK-way K-split. TRI=1 skip.
// SWZ=1: XCD-swizzled 1-D grid.
// ---------------------------------------------------------------------------
template<int TA, int TB, int SK, int TRI, int SWZ, int EPIB>
__global__ __launch_bounds__(256)
void mm_kernel(const float* __restrict__ Aall, const float* __restrict__ Ball,
               float* __restrict__ Call,
               int M, int N, int K, int planeK,
               int lda, int ldb, int ldc,
               long sA, long sB, long sC, long pA, long pB, long sSplit, int MT)
{
    int nx, my, zz;
    if (SWZ) {
        int id = blockIdx.x;
        int x8 = id & 7;
        int q  = id >> 3;
        nx = q % 9;
        int band = x8 + 8 * (q / 9);
        if (band >= MT * 4 * SK) return;
        my = band % MT;
        zz = band / MT;
    } else { nx = blockIdx.x; my = blockIdx.y; zz = blockIdx.z; }
    int sp = (SK > 1) ? (zz % SK) : 0;
    int b  = (SK > 1) ? (zz / SK) : zz;
    const float* A = Aall + (size_t)b * sA;
    const float* B = Ball + (size_t)b * sB;
    float* C = Call + (size_t)b * sC + (size_t)sp * sSplit;
    int n0 = nx * 64;
    int m0 = my * 64;

    __shared__ float As[16][68];
    __shared__ float Bs[16][68];

    int tid = threadIdx.x;
    int tx = tid & 15, ty = tid >> 4;

    float acc[4][4] = {};
    bool mFull = (m0 + 64 <= M);
    bool nFull = (n0 + 64 <= N);

    int triBeg = 0;
    if (TRI) { int mx = (m0 > n0 ? m0 : n0); triBeg = mx & ~15; }
    int kBeg = triBeg, kEnd = K;
    if (SK > 1) {
        int len = K - triBeg;
        int chunk = ((len / SK) + 15) & ~15;
        kBeg = triBeg + sp * chunk;
        if (kBeg > K) kBeg = K;
        kEnd = (sp == SK - 1) ? K : (kBeg + chunk < K ? kBeg + chunk : K);
    }

    float avr[4];
    float bvr[4];

    auto loadA = [&](int k0) {
        int plane = k0 / planeK;
        int koff  = k0 - plane * planeK;
        if (TA == 0) {
            const float* Ab = A + (size_t)pA * plane;
            int r = tid >> 2, c4 = (tid & 3) * 4;
            int gm = m0 + r;
            if (mFull || gm < M) {
                float4 t = *(const float4*)(Ab + (size_t)gm * lda + koff + c4);
                avr[0]=t.x; avr[1]=t.y; avr[2]=t.z; avr[3]=t.w;
            } else { avr[0]=avr[1]=avr[2]=avr[3]=0.0f; }
        } else {
            int r = tid >> 4, c4 = (tid & 15) * 4;
            const float* p = A + (size_t)(koff + r) * lda + m0 + c4;
            if (mFull) {
                float4 t = *(const float4*)p;
                avr[0]=t.x; avr[1]=t.y; avr[2]=t.z; avr[3]=t.w;
            } else {
                #pragma unroll
                for (int jj = 0; jj < 4; ++jj)
                    avr[jj] = (m0 + c4 + jj < M) ? p[jj] : 0.0f;
            }
        }
    };
    auto storeA = [&]() {
        if (TA == 0) {
            int r = tid >> 2, c4 = (tid & 3) * 4;
            #pragma unroll
            for (int q = 0; q < 4; ++q) As[c4+q][r] = avr[q];
        } else {
            int r = tid >> 4, c4 = (tid & 15) * 4;
            #pragma unroll
            for (int q = 0; q < 4; ++q) As[r][c4+q] = avr[q];
        }
    };
    auto loadB = [&](int k0) {
        int plane = k0 / planeK;
        int koff  = k0 - plane * planeK;
        if (TB == 0) {
            int r = tid >> 4, c4 = (tid & 15) * 4;
            const float* p = B + (size_t)(koff + r) * ldb + n0 + c4;
            if (nFull) {
                float4 t = *(const float4*)p;
                bvr[0]=t.x; bvr[1]=t.y; bvr[2]=t.z; bvr[3]=t.w;
            } else {
                #pragma unroll
                for (int jj = 0; jj < 4; ++jj)
                    bvr[jj] = (n0 + c4 + jj < N) ? p[jj] : 0.0f;
            }
        } else {
            const float* Bb = B + (size_t)pB * plane;
            int r = tid >> 2, c4 = (tid & 3) * 4;
            int gp = n0 + r;
            if (nFull || gp < N) {
                float4 t = *(const float4*)(Bb + (size_t)gp * ldb + koff + c4);
                bvr[0]=t.x; bvr[1]=t.y; bvr[2]=t.z; bvr[3]=t.w;
            } else { bvr[0]=bvr[1]=bvr[2]=bvr[3]=0.0f; }
        }
    };
    auto storeB = [&]() {
        if (TB == 0) {
            int r = tid >> 4, c4 = (tid & 15) * 4;
            #pragma unroll
            for (int q = 0; q < 4; ++q) Bs[r][c4+q] = bvr[q];
        } else {
            int r = tid >> 2, c4 = (tid & 3) * 4;
            #pragma unroll
            for (int q = 0; q < 4; ++q) Bs[c4+q][r] = bvr[q];
        }
    };

    if (kBeg < kEnd) {
        loadA(kBeg); loadB(kBeg);
        for (int k0 = kBeg; k0 < kEnd; k0 += 16) {
            storeA(); storeB();
            __syncthreads();
            if (k0 + 16 < kEnd) { loadA(k0 + 16); loadB(k0 + 16); }
            #pragma unroll
            for (int kk = 0; kk < 16; ++kk) {
                float a[4], bb[4];
                *(float4*)a  = *(const float4*)&As[kk][ty*4];
                *(float4*)bb = *(const float4*)&Bs[kk][tx*4];
                #pragma unroll
                for (int i = 0; i < 4; ++i)
                    #pragma unroll
                    for (int j = 0; j < 4; ++j)
                        acc[i][j] += a[i] * bb[j];
            }
            __syncthreads();
        }
    }

    #pragma unroll
    for (int i = 0; i < 4; ++i) {
        int gm = m0 + ty*4 + i;
        if (gm >= M) continue;
        #pragma unroll
        for (int j = 0; j < 4; ++j) {
            int gn = n0 + tx*4 + j;
            if (gn >= N) continue;
            C[(size_t)gm * ldc + gn] = acc[i][j];
        }
    }
}

// ---------------------------------------------------------------------------
// combine kernels
// ---------------------------------------------------------------------------
__global__ void combine_add2(const float* __restrict__ p0, float* __restrict__ o,
                             long stride) {
    int i = blockIdx.x * 256 + threadIdx.x;   // float4 over 4*N2
    float4 x = ((const float4*)p0)[i];
    float4 y = ((const float4*)(p0 + stride))[i];
    float4 r; r.x=x.x+y.x; r.y=x.y+y.y; r.z=x.z+y.z; r.w=x.w+y.w;
    ((float4*)o)[i] = r;
}

__global__ void combine_solm4(const float* __restrict__ p, float* __restrict__ o) {
    int i = blockIdx.x * 256 + threadIdx.x;   // 73728 elems -> 288 WGs
    o[i] = p[i] + p[i + 73728] + p[i + 2*73728] + p[i + 3*73728];
}

__global__ void combine_prior4(const float* __restrict__ p0,
                               const float* __restrict__ xin,
                               const float* __restrict__ W2g,
                               float* __restrict__ o, long stride) {
    __shared__ float w[16];
    int tid = threadIdx.x;
    if (tid < 16) w[tid] = W2g[tid];
    __syncthreads();
    int idx = blockIdx.x * 256 + tid;           // over 4*N2
    int b = idx / N2;
    int rem = idx - b * N2;
    int m = rem / NPTS, n = rem - m * NPTS;
    const float* xb = xin + (size_t)b * NPTS * 2;
    float r0 = xb[m*2+0] - xb[n*2+0];
    float r1 = xb[m*2+1] - xb[n*2+1];
    float u = (r0*r0 + r1*r1) * INVL2;
    float Kv = expf(-0.5f * u);
    float i2 = INVL2 * INVL2;
    float gK0 = r0 * INVL2 * Kv;
    float gK1 = r1 * INVL2 * Kv;
    float lapK = (u - 2.0f) * INVL2 * Kv;
    float gg00 = (INVL2 - r0*r0*i2) * Kv;
    float gg01 = (-r0*r1*i2) * Kv;
    float gg11 = (INVL2 - r1*r1*i2) * Kv;
    float gl0 = r0 * i2 * (4.0f - u) * Kv;
    float gl1 = r1 * i2 * (4.0f - u) * Kv;
    float ll = ((u-2.0f)*(u-2.0f) - 4.0f*u + 4.0f) * i2 * Kv;
    float prior =
          w[0]*Kv + w[1]*gK0 + w[2]*gK1 + w[3]*lapK
        + w[4]*(-gK0) + w[5]*gg00 + w[6]*gg01 + w[7]*gl0
        + w[8]*(-gK1) + w[9]*gg01 + w[10]*gg11 + w[11]*gl1
        + w[12]*lapK + w[13]*(-gl0) + w[14]*(-gl1) + w[15]*ll;
    float v = p0[idx] + p0[idx + stride] + p0[idx + 2*stride] + p0[idx + 3*stride]
            + prior;
    if (m == n) v += 1.1e-4f;
    o[idx] = v;
}

// ---------------------------------------------------------------------------
// opiKW2[b][i] = sum_j W2[i][j] * opiK[b][j]  — safe in-place (per-element)
// ---------------------------------------------------------------------------
__global__ void opiw2_k(const float* __restrict__ opiK, const float* __restrict__ W2,
                        float* __restrict__ outB) {
    int idx = blockIdx.x * 256 + threadIdx.x;
    int b = idx / N2;
    int rem = idx - b * N2;
    size_t base = (size_t)b * 4 * N2 + rem;
    float k0 = opiK[base], k1 = opiK[base + N2], k2 = opiK[base + 2*N2], k3 = opiK[base + 3*N2];
    #pragma unroll
    for (int i = 0; i < 4; ++i)
        outB[base + (size_t)i * N2] = W2[i*4+0]*k0 + W2[i*4+1]*k1 + W2[i*4+2]*k2 + W2[i*4+3]*k3;
}

// ---------------------------------------------------------------------------
__global__ __launch_bounds__(256)
void amean_k(const float* __restrict__ opimean, const float* __restrict__ weight,
             const float* __restrict__ bias, float* __restrict__ out) {
    int b = blockIdx.y;
    int m0 = blockIdx.x * 32;
    __shared__ float Wl[64][128];
    __shared__ float om[32][128];
    int tid = threadIdx.x;
    for (int idx = tid; idx < 64*128; idx += 256) Wl[idx / 128][idx & 127] = weight[idx];
    for (int idx = tid; idx < 32*128; idx += 256) {
        int m = idx >> 7, ck = idx & 127, c = ck >> 2, kop = ck & 3;
        om[m][ck] = opimean[((size_t)b * 4 + kop) * NPTS * 32 + (size_t)(m0 + m) * 32 + c];
    }
    __syncthreads();
    int ml = tid >> 3, o0 = (tid & 7) * 8;
    float acc[8] = {};
    for (int ck = 0; ck < 128; ++ck) {
        float v = om[ml][ck];
        #pragma unroll
        for (int q = 0; q < 8; ++q) acc[q] += v * Wl[o0+q][ck];
    }
    #pragma unroll
    for (int q = 0; q < 8; ++q)
        out[4608 + ((size_t)b * NPTS + m0 + ml) * 64 + o0 + q] = acc[q] + bias[o0+q];
}

// ---------------------------------------------------------------------------
static inline int gridSwz(int MT, int Z) { return 8 * 9 * ((MT * Z + 7) / 8); }

extern "C" void kernel_launch(void* const* d_in, const int* in_sizes, int n_in,
                              void* d_out, int out_size, void* d_ws, size_t ws_size,
                              hipStream_t stream) {
    const float* xin    = (const float*)d_in[0];
    const float* meanin = (const float*)d_in[1];
    const float* Kin    = (const float*)d_in[2];
    const float* weight = (const float*)d_in[3];
    const float* bias   = (const float*)d_in[4];
    float* out = (float*)d_out;
    float* ws  = (float*)d_ws;

    const long N2L = N2;
    float* W2      = ws;                       // 16 (pad 64)
    float* LinvKK  = ws + 64;                  // 4*9*4096
    float* R1 = LinvKK + 147456;               // 4*N2: Kxx/A; later iW (Kin@Kinv)
    float* R2 = R1 + 4*N2L;                    // 4*N2: Linv; later solm/opim
    float* R3 = R2 + 4*N2L;                    // 4*N2: L panels; later Kinv
    float* R4 = R3 + 4*N2L;                    // 16*N2: opiK; later opiKW2 (in-place)
    float* R5 = R4 + 16*N2L;                   // 16*N2: Kinv partials; KiO; final partials
    float* R6 = R5 + 16*N2L;                   // 16*N2: solm partials; H'

    // zero Linv (upper triangle must be 0)
    hipMemsetAsync(R2, 0, (size_t)4 * N2 * sizeof(float), stream);
    copy_xout<<<dim3(18), dim3(256), 0, stream>>>(xin, out);
    build_k<<<dim3((BSZ*N2)/256), dim3(256), 0, stream>>>(xin, R1, R4);
    w2_k<<<dim3(1), dim3(256), 0, stream>>>(weight, W2);
    // Cholesky: 9 launches. L panels -> R3; diag inverses -> LinvKK
    chol_diag0<<<dim3(BSZ), dim3(256), 0, stream>>>(R1, LinvKK);
    for (int kb = 0; kb < NT - 1; ++kb) {
        int t = NT - 1 - kb;
        chol_step<<<dim3(t*(t+1)/2, BSZ), dim3(256), 0, stream>>>(R1, R3, LinvKK, kb);
    }
    // triangular inverse -> R2
    trinv_blk<<<dim3(4, NT, BSZ), dim3(256), 0, stream>>>(R3, LinvKK, R2);
    // Kinv = Linv^T @ Linv  (SK2+tri, swizzled; partials -> R5; combine -> R3)
    mm_kernel<1,0,2,1,1,0><<<dim3(gridSwz(9,8)), dim3(256), 0, stream>>>(
        R2, R2, R5, 576,576,576,576, 576,576,576,
        N2L,N2L,N2L, 0,0, 4*N2L, 9);
    combine_add2<<<dim3(1296), dim3(256), 0, stream>>>(R5, R3, 4*N2L);
    // sol_mean = Kinv @ meanin  (SK4 partials -> R6; combine -> R2)
    mm_kernel<0,0,4,0,0,0><<<dim3(1,9,16), dim3(256), 0, stream>>>(
        R3, meanin, R6, 576,32,576,576, 576,32,32,
        N2L,18432,18432, 0,0, 73728, 9);
    combine_solm4<<<dim3(288), dim3(256), 0, stream>>>(R6, R2);
    // opimean = opiK @ sol_mean -> R2+73728
    mm_kernel<0,0,1,0,0,0><<<dim3(1,36,BSZ), dim3(256), 0, stream>>>(
        R4, R2, R2 + 73728, 2304,32,576,576, 576,32,32,
        4*N2L,18432,73728, 0,0, 0, 9);
    amean_k<<<dim3(18,BSZ), dim3(256), 0, stream>>>(R2 + 73728, weight, bias, out);
    // iW = Kin @ Kinv  (SK1, swizzled) -> R1  (-I folded into H' B-load)
    mm_kernel<0,0,1,0,1,0><<<dim3(gridSwz(9,4)), dim3(256), 0, stream>>>(
        Kin, R3, R1, 576,576,576,576, 576,576,576,
        N2L,N2L,N2L, 0,0, 0, 9);
    // KiO = opiK @ Kinv  (1-wave 8x8, swizzled) -> R5
    mm64<0,1,0><<<dim3(gridSwz(36,4)), dim3(64), 0, stream>>>(
        R4, R3, R5, 576,576, 576,576,576,
        4*N2L, N2L, 4*N2L, 0,0, 0, 36);
    // opiKW2 in-place on R4 (opiK no longer needed)
    opiw2_k<<<dim3((BSZ*N2)/256), dim3(256), 0, stream>>>(R4, W2, R4);
    // H' = KiO @ (iW - I)  (1-wave 8x8, swizzled, -I fold) -> R6
    mm64<0,1,1><<<dim3(gridSwz(36,4)), dim3(64), 0, stream>>>(
        R5, R1, R6, 576,576, 576,576,576,
        4*N2L, N2L, 4*N2L, 0,0, 0, 36);
    // final AKA partial GEMM (1-wave 8x8, SK4, swizzled): partials -> R5
    // sC = N2 (batch stride), sSplit = 4*N2 (split stride) — distinct planes.
    mm64<1,4,0><<<dim3(gridSwz(9,16)), dim3(64), 0, stream>>>(
        R6, R4, R5, 2304,576, 576,576,576,
        4*N2L, 4*N2L, N2L, N2L,N2L, 4*N2L, 9);
    // output 2: combine 4 partials + analytic prior + jitter
    combine_prior4<<<dim3(5184), dim3(256), 0, stream>>>(
        R5, xin, W2, out + 152064, 4*N2L);
}

// Round 10
// 1451.449 us; speedup vs baseline: 1.0087x; 1.0087x over previous
//
#include <hip/hip_runtime.h>
#include <math.h>

#define NPTS 576
#define N2 331776           // 576*576
#define BSZ 4
#define NB 64               // cholesky block
#define NT 9                // 576/64

#define INVL2 (1.0f/0.29311396f)

// ---------------------------------------------------------------------------
__global__ void copy_xout(const float* __restrict__ xin, float* __restrict__ out) {
    int idx = blockIdx.x * 256 + threadIdx.x;   // 18*256 = 4608 exact
    out[idx] = xin[idx];
}

// ---------------------------------------------------------------------------
// build Kxx (+jitter) and opiK (4 planes) from xin
// ---------------------------------------------------------------------------
__global__ void build_k(const float* __restrict__ xin,
                        float* __restrict__ Kxx, float* __restrict__ opiK) {
    int idx = blockIdx.x * 256 + threadIdx.x;
    int b = idx / N2;
    int rem = idx - b * N2;
    int m = rem / NPTS;
    int nn = rem - m * NPTS;
    const float* xb = xin + (size_t)b * NPTS * 2;
    float xm0 = xb[m*2],  xm1 = xb[m*2+1];
    float xn0 = xb[nn*2], xn1 = xb[nn*2+1];
    float r0 = xm0 - xn0, r1 = xm1 - xn1;
    float u = (r0*r0 + r1*r1) * INVL2;
    float Kv = expf(-0.5f * u);
    Kxx[idx] = Kv + ((m == nn) ? 1e-5f : 0.0f);
    size_t base = (size_t)b * 4 * N2 + rem;
    opiK[base]          = Kv;
    opiK[base + N2]     = -r0 * INVL2 * Kv;
    opiK[base + 2*N2]   = -r1 * INVL2 * Kv;
    opiK[base + 3*N2]   = (u - 2.0f) * INVL2 * Kv;
}

// ---------------------------------------------------------------------------
__global__ void w2_k(const float* __restrict__ w, float* __restrict__ W2) {
    __shared__ float red[256];
    int tid = threadIdx.x;
    int pair = tid & 15;
    int slice = tid >> 4;
    int i = pair >> 2, j = pair & 3;
    float s = 0.0f;
    for (int o = slice * 4; o < slice * 4 + 4; ++o)
        for (int c = 0; c < 32; ++c)
            s += w[o*128 + c*4 + i] * w[o*128 + c*4 + j];
    red[tid] = s;
    __syncthreads();
    if (tid < 16) {
        float t = 0.0f;
        #pragma unroll
        for (int k = 0; k < 16; ++k) t += red[pair + 16*k];
        W2[pair] = t * (1.0f/64.0f);
    }
}

// ---------------------------------------------------------------------------
// factor 64x64 SPD block in T (lower), produce V = T^{-1} (lower).
// ---------------------------------------------------------------------------
__device__ void factor_invert_64(float (*T)[NB+1], float (*V)[NB+1],
                                 float (*tmp)[17], int tid) {
    for (int p = 0; p < 4; ++p) {
        int cp = p * 16;
        if (tid < 64) {
            int r = tid;
            #pragma unroll 1
            for (int j = 0; j < 16; ++j) {
                int col = cp + j;
                if (r == col) T[col][col] = sqrtf(fmaxf(T[col][col], 1e-12f));
                float d = T[col][col];
                float lr = 0.0f;
                if (r > col) { lr = T[r][col] / d; T[r][col] = lr; }
                #pragma unroll 1
                for (int c = col + 1; c < cp + 16; ++c) {
                    float lc = T[c][col];
                    if (r >= c) T[r][c] -= lr * lc;
                }
            }
        }
        __syncthreads();
        int tr = 48 - cp;
        if (tr > 0) {
            for (int idx = tid; idx < tr * tr; idx += 256) {
                int r = cp + 16 + idx / tr;
                int c = cp + 16 + idx % tr;
                if (c <= r) {
                    float s = 0.0f;
                    #pragma unroll
                    for (int k = 0; k < 16; ++k) s += T[r][cp+k] * T[c][cp+k];
                    T[r][c] -= s;
                }
            }
        }
        __syncthreads();
    }
    if (tid < 64) {
        int I = tid >> 4, c = tid & 15, base = I * 16;
        for (int i = c; i < 16; ++i) {
            float s = (i == c) ? 1.0f : 0.0f;
            for (int k = c; k < i; ++k) s -= T[base+i][base+k] * V[base+k][base+c];
            V[base+i][base+c] = s / T[base+i][base+i];
        }
    }
    __syncthreads();
    const int PI[6] = {1,2,3,2,3,3};
    const int PJ[6] = {0,1,2,0,1,0};
    int rr16 = tid >> 4, cc16 = tid & 15;
    for (int p = 0; p < 6; ++p) {
        int I = PI[p], J = PJ[p];
        float s = 0.0f;
        for (int K = J; K < I; ++K)
            #pragma unroll
            for (int t = 0; t < 16; ++t)
                s += T[I*16+rr16][K*16+t] * V[K*16+t][J*16+cc16];
        tmp[rr16][cc16] = s;
        __syncthreads();
        float s2 = 0.0f;
        for (int t = 0; t <= rr16; ++t) s2 += V[I*16+rr16][I*16+t] * tmp[t][cc16];
        __syncthreads();
        V[I*16+rr16][J*16+cc16] = -s2;
        __syncthreads();
    }
}

// ---------------------------------------------------------------------------
__global__ void chol_diag0(const float* __restrict__ A, float* __restrict__ LinvKK) {
    int b = blockIdx.x;
    const float* Ab = A + (size_t)b * N2;
    __shared__ float T[NB][NB+1];
    __shared__ float V[NB][NB+1];
    __shared__ float tmp[16][17];
    int tid = threadIdx.x;
    for (int idx = tid; idx < NB*NB; idx += 256) {
        int r = idx >> 6, c = idx & 63;
        T[r][c] = Ab[(size_t)r * NPTS + c];
        V[r][c] = 0.0f;
    }
    __syncthreads();
    factor_invert_64(T, V, tmp, tid);
    float* Vg = LinvKK + (size_t)b * NT * NB * NB;
    for (int idx = tid; idx < NB*NB; idx += 256) Vg[idx] = V[idx >> 6][idx & 63];
}

// ---------------------------------------------------------------------------
// fused Cholesky step for panel kb. 9 total launches.
// ---------------------------------------------------------------------------
__global__ __launch_bounds__(256)
void chol_step(float* __restrict__ A, float* __restrict__ LL,
               float* __restrict__ LinvKK, int kb) {
    int b = blockIdx.y;
    int p = blockIdx.x;
    int ir = 0;
    while (p >= ir + 1) { p -= ir + 1; ir++; }
    int ib = kb + 1 + ir, jb = kb + 1 + p;
    float* Ab = A + (size_t)b * N2;
    float* LLb = LL + (size_t)b * N2;
    __shared__ float Ai[NB][NB+1];
    __shared__ float Aj[NB][NB+1];
    __shared__ float Vs[NB][NB+1];
    __shared__ float tmp[16][17];
    int tid = threadIdx.x;
    int tx = tid & 15, ty = tid >> 4;
    const float* Vg = LinvKK + ((size_t)b * NT + kb) * NB * NB;
    bool diag = (ib == jb);
    for (int idx = tid; idx < NB*NB; idx += 256) {
        int r = idx >> 6, c = idx & 63;
        Ai[r][c] = Ab[(size_t)(ib*NB + r) * NPTS + kb*NB + c];
        Aj[r][c] = diag ? 0.0f : Ab[(size_t)(jb*NB + r) * NPTS + kb*NB + c];
        Vs[r][c] = Vg[idx];
    }
    float U[4][4];
    #pragma unroll
    for (int i = 0; i < 4; ++i)
        #pragma unroll
        for (int j = 0; j < 4; ++j)
            U[i][j] = Ab[(size_t)(ib*NB + ty*4+i) * NPTS + jb*NB + tx*4+j];
    __syncthreads();
    float Li[4][4] = {}, Lj[4][4] = {};
    for (int k = 0; k < NB; ++k) {
        float a[4], v[4];
        #pragma unroll
        for (int i = 0; i < 4; ++i) a[i] = Ai[ty*4+i][k];
        #pragma unroll
        for (int j = 0; j < 4; ++j) v[j] = Vs[tx*4+j][k];
        #pragma unroll
        for (int i = 0; i < 4; ++i)
            #pragma unroll
            for (int j = 0; j < 4; ++j) Li[i][j] += a[i] * v[j];
        if (!diag) {
            float aj[4];
            #pragma unroll
            for (int i = 0; i < 4; ++i) aj[i] = Aj[ty*4+i][k];
            #pragma unroll
            for (int i = 0; i < 4; ++i)
                #pragma unroll
                for (int j = 0; j < 4; ++j) Lj[i][j] += aj[i] * v[j];
        }
    }
    __syncthreads();
    #pragma unroll
    for (int i = 0; i < 4; ++i)
        #pragma unroll
        for (int j = 0; j < 4; ++j) {
            Ai[ty*4+i][tx*4+j] = Li[i][j];
            Aj[ty*4+i][tx*4+j] = diag ? Li[i][j] : Lj[i][j];
        }
    if (diag) {
        #pragma unroll
        for (int i = 0; i < 4; ++i)
            #pragma unroll
            for (int j = 0; j < 4; ++j)
                LLb[(size_t)(ib*NB + ty*4+i) * NPTS + kb*NB + tx*4+j] = Li[i][j];
    }
    __syncthreads();
    float s[4][4] = {};
    for (int k = 0; k < NB; ++k) {
        float a[4], v[4];
        #pragma unroll
        for (int i = 0; i < 4; ++i) a[i] = Ai[ty*4+i][k];
        #pragma unroll
        for (int j = 0; j < 4; ++j) v[j] = Aj[tx*4+j][k];
        #pragma unroll
        for (int i = 0; i < 4; ++i)
            #pragma unroll
            for (int j = 0; j < 4; ++j) s[i][j] += a[i] * v[j];
    }
    #pragma unroll
    for (int i = 0; i < 4; ++i)
        #pragma unroll
        for (int j = 0; j < 4; ++j) U[i][j] -= s[i][j];
    if (blockIdx.x != 0) {
        #pragma unroll
        for (int i = 0; i < 4; ++i)
            #pragma unroll
            for (int j = 0; j < 4; ++j)
                Ab[(size_t)(ib*NB + ty*4+i) * NPTS + jb*NB + tx*4+j] = U[i][j];
        return;
    }
    __syncthreads();
    #pragma unroll
    for (int i = 0; i < 4; ++i)
        #pragma unroll
        for (int j = 0; j < 4; ++j) Ai[ty*4+i][tx*4+j] = U[i][j];
    for (int idx = tid; idx < NB*NB; idx += 256) Aj[idx >> 6][idx & 63] = 0.0f;
    __syncthreads();
    factor_invert_64(Ai, Aj, tmp, tid);
    float* Vo = LinvKK + ((size_t)b * NT + (kb + 1)) * NB * NB;
    for (int idx = tid; idx < NB*NB; idx += 256) Vo[idx] = Aj[idx >> 6][idx & 63];
}

// ---------------------------------------------------------------------------
// blocked triangular inverse. grid (4 col-splits, 9 block-cols, 4 batch)
// ---------------------------------------------------------------------------
__global__ __launch_bounds__(256)
void trinv_blk(const float* __restrict__ L, const float* __restrict__ LinvKK,
               float* __restrict__ Linv) {
    int sp = blockIdx.x, jb = blockIdx.y, b = blockIdx.z;
    const float* Lb = L + (size_t)b * N2;
    float* Xg = Linv + (size_t)b * N2;
    const float* Vg = LinvKK + (size_t)b * NT * NB * NB;
    int c0 = jb * NB + sp * 16;

    __shared__ float LsT[64][72];
    __shared__ float Xc[576][17];
    __shared__ float Ss[64][17];

    int tid = threadIdx.x;
    int tx = tid & 15, ty = tid >> 4;

    {
        const float* Vjj = Vg + (size_t)jb * NB * NB;
        int r = tid >> 2, c4 = (tid & 3) * 4;
        float4 v = *(const float4*)(Vjj + r * NB + sp * 16 + c4);
        Xc[r][c4+0] = v.x; Xc[r][c4+1] = v.y; Xc[r][c4+2] = v.z; Xc[r][c4+3] = v.w;
        *(float4*)(Xg + (size_t)(jb * NB + r) * NPTS + c0 + c4) = v;
    }
    __syncthreads();

    for (int ib = jb + 1; ib < NT; ++ib) {
        float acc[4] = {};
        for (int kb = jb; kb < ib; ++kb) {
            {
                int r = tid >> 2, t0 = (tid & 3) * 16;
                const float* src = Lb + (size_t)(ib * NB + r) * NPTS + kb * NB + t0;
                #pragma unroll
                for (int q = 0; q < 4; ++q) {
                    float4 v = *(const float4*)(src + q * 4);
                    LsT[t0 + q*4 + 0][r] = v.x;
                    LsT[t0 + q*4 + 1][r] = v.y;
                    LsT[t0 + q*4 + 2][r] = v.z;
                    LsT[t0 + q*4 + 3][r] = v.w;
                }
            }
            __syncthreads();
            int xbase = (kb - jb) * 64;
            #pragma unroll 8
            for (int t = 0; t < 64; ++t) {
                float a4[4]; *(float4*)a4 = *(const float4*)&LsT[t][ty*4];
                float xv = Xc[xbase + t][tx];
                #pragma unroll
                for (int i = 0; i < 4; ++i) acc[i] += a4[i] * xv;
            }
            __syncthreads();
        }
        #pragma unroll
        for (int i = 0; i < 4; ++i) Ss[ty*4+i][tx] = acc[i];
        {
            const float* Vii = Vg + (size_t)ib * NB * NB;
            int r = tid >> 2, t0 = (tid & 3) * 16;
            #pragma unroll
            for (int q = 0; q < 4; ++q) {
                float4 v = *(const float4*)(Vii + r * NB + t0 + q * 4);
                LsT[t0 + q*4 + 0][r] = v.x;
                LsT[t0 + q*4 + 1][r] = v.y;
                LsT[t0 + q*4 + 2][r] = v.z;
                LsT[t0 + q*4 + 3][r] = v.w;
            }
        }
        __syncthreads();
        float acc2[4] = {};
        #pragma unroll 8
        for (int t = 0; t < 64; ++t) {
            float a4[4]; *(float4*)a4 = *(const float4*)&LsT[t][ty*4];
            float sv = Ss[t][tx];
            #pragma unroll
            for (int i = 0; i < 4; ++i) acc2[i] += a4[i] * sv;
        }
        int obase = (ib - jb) * 64;
        #pragma unroll
        for (int i = 0; i < 4; ++i) {
            float v = -acc2[i];
            Xc[obase + ty*4 + i][tx] = v;
            Xg[(size_t)(ib * NB + ty*4 + i) * NPTS + c0 + tx] = v;
        }
        __syncthreads();
    }
}

// ---------------------------------------------------------------------------
// mm128: 128x128 tile, 256 threads, 8x(2x4) micro-tile (B/MAC = 1.0).
// n-fragment split into two 64-halves so b128 reads are 2-way/broadcast.
// 64-granular bounds (all dims here are multiples of 64). TB=1: C = A B^T.
// SK-way K-split; XCD-swizzled 1-D grid with runtime NX.
// EPIB=1: B := B - I during load (TB=0 only).
// ---------------------------------------------------------------------------
template<int TB, int SK, int EPIB>
__global__ __launch_bounds__(256)
void mm128(const float* __restrict__ Aall, const float* __restrict__ Ball,
           float* __restrict__ Call,
           int M, int N, int K, int planeK,
           int lda, int ldb, int ldc,
           long sA, long sB, long sC, long pA, long pB, long sSplit,
           int MT, int NX)
{
    int id = blockIdx.x;
    int x8 = id & 7, qq = id >> 3;
    int nx = qq % NX;
    int band = x8 + 8 * (qq / NX);
    if (band >= MT * BSZ * SK) return;
    int my = band % MT;
    int zz = band / MT;
    int sp = (SK > 1) ? (zz % SK) : 0;
    int b  = (SK > 1) ? (zz / SK) : zz;
    const float* A = Aall + (size_t)b * sA;
    const float* B = Ball + (size_t)b * sB;
    float* C = Call + (size_t)b * sC + (size_t)sp * sSplit;
    int n0 = nx * 128, m0 = my * 128;

    __shared__ float As[16][136];
    __shared__ float Bs[16][136];

    int tid = threadIdx.x;
    int tx = tid & 15, ty = tid >> 4;
    int r64 = tid >> 2, c4 = (tid & 3) * 4;

    bool mOK1 = (m0 + 64 < M);       // half-1 of m valid (half-0 always valid)
    bool nOK1 = (n0 + 64 < N);

    float acc[8][2][4] = {};

    int kBeg = 0, kEnd = K;
    if (SK > 1) {
        int chunk = ((K / SK) + 15) & ~15;
        kBeg = sp * chunk;
        if (kBeg > K) kBeg = K;
        kEnd = (sp == SK - 1) ? K : (kBeg + chunk < K ? kBeg + chunk : K);
    }

    float ap[2][4], bp[2][4];

    auto loadA = [&](int k0) {
        int plane = k0 / planeK;
        int koff  = k0 - plane * planeK;
        const float* Ab = A + (size_t)pA * plane + koff + c4;
        #pragma unroll
        for (int h = 0; h < 2; ++h) {
            int gm = m0 + h*64 + r64;
            if (h == 0 || mOK1) {
                float4 t = *(const float4*)(Ab + (size_t)gm * lda);
                ap[h][0]=t.x; ap[h][1]=t.y; ap[h][2]=t.z; ap[h][3]=t.w;
            } else { ap[h][0]=ap[h][1]=ap[h][2]=ap[h][3]=0.0f; }
        }
    };
    auto storeA = [&]() {
        #pragma unroll
        for (int h = 0; h < 2; ++h)
            #pragma unroll
            for (int q = 0; q < 4; ++q)
                As[c4+q][h*64 + r64] = ap[h][q];
    };
    auto loadB = [&](int k0) {
        int plane = k0 / planeK;
        int koff  = k0 - plane * planeK;
        if (TB == 0) {
            // row = ty (k), cols n0 + tx*8 .. +7 (same 64-half: tx>>3)
            const float* p0 = B + (size_t)(koff + ty) * ldb + n0 + tx*8;
            bool ok = (tx < 8) || nOK1;
            if (ok) {
                float4 t0 = *(const float4*)p0;
                float4 t1 = *(const float4*)(p0 + 4);
                bp[0][0]=t0.x; bp[0][1]=t0.y; bp[0][2]=t0.z; bp[0][3]=t0.w;
                bp[1][0]=t1.x; bp[1][1]=t1.y; bp[1][2]=t1.z; bp[1][3]=t1.w;
            } else {
                #pragma unroll
                for (int q = 0; q < 4; ++q) { bp[0][q]=0.0f; bp[1][q]=0.0f; }
            }
            if (EPIB) {
                int gk = koff + ty;
                #pragma unroll
                for (int q = 0; q < 8; ++q)
                    if (gk == n0 + tx*8 + q) bp[q>>2][q&3] -= 1.0f;
            }
        } else {
            const float* Bb = B + (size_t)pB * plane + koff + c4;
            #pragma unroll
            for (int h = 0; h < 2; ++h) {
                int gn = n0 + h*64 + r64;
                if (h == 0 || nOK1) {
                    float4 t = *(const float4*)(Bb + (size_t)gn * ldb);
                    bp[h][0]=t.x; bp[h][1]=t.y; bp[h][2]=t.z; bp[h][3]=t.w;
                } else { bp[h][0]=bp[h][1]=bp[h][2]=bp[h][3]=0.0f; }
            }
        }
    };
    auto storeB = [&]() {
        if (TB == 0) {
            *(float4*)&Bs[ty][tx*8]     = *(float4*)bp[0];
            *(float4*)&Bs[ty][tx*8 + 4] = *(float4*)bp[1];
        } else {
            #pragma unroll
            for (int h = 0; h < 2; ++h)
                #pragma unroll
                for (int q = 0; q < 4; ++q)
                    Bs[c4+q][h*64 + r64] = bp[h][q];
        }
    };

    if (kBeg < kEnd) {
        loadA(kBeg); loadB(kBeg);
        for (int k0 = kBeg; k0 < kEnd; k0 += 16) {
            storeA(); storeB();
            __syncthreads();
            if (k0 + 16 < kEnd) { loadA(k0 + 16); loadB(k0 + 16); }
            #pragma unroll
            for (int kk = 0; kk < 16; ++kk) {
                float a[8], bb[2][4];
                *(float4*)a       = *(const float4*)&As[kk][ty*8];
                *(float4*)(a + 4) = *(const float4*)&As[kk][ty*8 + 4];
                *(float4*)bb[0]   = *(const float4*)&Bs[kk][tx*4];
                *(float4*)bb[1]   = *(const float4*)&Bs[kk][64 + tx*4];
                #pragma unroll
                for (int i = 0; i < 8; ++i)
                    #pragma unroll
                    for (int jh = 0; jh < 2; ++jh)
                        #pragma unroll
                        for (int j = 0; j < 4; ++j)
                            acc[i][jh][j] += a[i] * bb[jh][j];
            }
            __syncthreads();
        }
    }

    bool rowOK = (ty < 8) || mOK1;   // rows ty*8..+7 live in half ty>>3
    if (rowOK) {
        #pragma unroll
        for (int i = 0; i < 8; ++i) {
            int gm = m0 + ty*8 + i;
            float* Cr = C + (size_t)gm * ldc + n0;
            #pragma unroll
            for (int jh = 0; jh < 2; ++jh) {
                if (jh == 1 && !nOK1) continue;
                float4 v;
                v.x = acc[i][jh][0]; v.y = acc[i][jh][1];
                v.z = acc[i][jh][2]; v.w = acc[i][jh][3];
                *(float4*)(Cr + jh*64 + tx*4) = v;
            }
        }
    }
}

// ---------------------------------------------------------------------------
// batched tiled matmul, 64x64 C-tile, 256 threads (4x4 micro) — cold GEMMs.
// TA=1: C=A^T B. SK-way K-split. TRI=1 skip. SWZ=1: XCD-swizzled (NX=9).
// ---------------------------------------------------------------------------
template<int TA, int TB, int SK, int TRI, int SWZ, int EPIB>
__global__ __launch_bounds__(256)
void mm_kernel(const float* __restrict__ Aall, const float* __restrict__ Ball,
               float* __restrict__ Call,
               int M, int N, int K, int planeK,
               int lda, int ldb, int ldc,
               long sA, long sB, long sC, long pA, long pB, long sSplit, int MT)
{
    int nx, my, zz;
    if (SWZ) {
        int id = blockIdx.x;
        int x8 = id & 7;
        int q  = id >> 3;
        nx = q % 9;
        int band = x8 + 8 * (q / 9);
        if (band >= MT * 4 * SK) return;
        my = band % MT;
        zz = band / MT;
    } else { nx = blockIdx.x; my = blockIdx.y; zz = blockIdx.z; }
    int sp = (SK > 1) ? (zz % SK) : 0;
    int b  = (SK > 1) ? (zz / SK) : zz;
    const float* A = Aall + (size_t)b * sA;
    const float* B = Ball + (size_t)b * sB;
    float* C = Call + (size_t)b * sC + (size_t)sp * sSplit;
    int n0 = nx * 64;
    int m0 = my * 64;

    __shared__ float As[16][68];
    __shared__ float Bs[16][68];

    int tid = threadIdx.x;
    int tx = tid & 15, ty = tid >> 4;

    float acc[4][4] = {};
    bool mFull = (m0 + 64 <= M);
    bool nFull = (n0 + 64 <= N);

    int triBeg = 0;
    if (TRI) { int mx = (m0 > n0 ? m0 : n0); triBeg = mx & ~15; }
    int kBeg = triBeg, kEnd = K;
    if (SK > 1) {
        int len = K - triBeg;
        int chunk = ((len / SK) + 15) & ~15;
        kBeg = triBeg + sp * chunk;
        if (kBeg > K) kBeg = K;
        kEnd = (sp == SK - 1) ? K : (kBeg + chunk < K ? kBeg + chunk : K);
    }

    float avr[4];
    float bvr[4];

    auto loadA = [&](int k0) {
        int plane = k0 / planeK;
        int koff  = k0 - plane * planeK;
        if (TA == 0) {
            const float* Ab = A + (size_t)pA * plane;
            int r = tid >> 2, c4 = (tid & 3) * 4;
            int gm = m0 + r;
            if (mFull || gm < M) {
                float4 t = *(const float4*)(Ab + (size_t)gm * lda + koff + c4);
                avr[0]=t.x; avr[1]=t.y; avr[2]=t.z; avr[3]=t.w;
            } else { avr[0]=avr[1]=avr[2]=avr[3]=0.0f; }
        } else {
            int r = tid >> 4, c4 = (tid & 15) * 4;
            const float* p = A + (size_t)(koff + r) * lda + m0 + c4;
            if (mFull) {
                float4 t = *(const float4*)p;
                avr[0]=t.x; avr[1]=t.y; avr[2]=t.z; avr[3]=t.w;
            } else {
                #pragma unroll
                for (int jj = 0; jj < 4; ++jj)
                    avr[jj] = (m0 + c4 + jj < M) ? p[jj] : 0.0f;
            }
        }
    };
    auto storeA = [&]() {
        if (TA == 0) {
            int r = tid >> 2, c4 = (tid & 3) * 4;
            #pragma unroll
            for (int q = 0; q < 4; ++q) As[c4+q][r] = avr[q];
        } else {
            int r = tid >> 4, c4 = (tid & 15) * 4;
            #pragma unroll
            for (int q = 0; q < 4; ++q) As[r][c4+q] = avr[q];
        }
    };
    auto loadB = [&](int k0) {
        int plane = k0 / planeK;
        int koff  = k0 - plane * planeK;
        if (TB == 0) {
            int r = tid >> 4, c4 = (tid & 15) * 4;
            const float* p = B + (size_t)(koff + r) * ldb + n0 + c4;
            if (nFull) {
                float4 t = *(const float4*)p;
                bvr[0]=t.x; bvr[1]=t.y; bvr[2]=t.z; bvr[3]=t.w;
            } else {
                #pragma unroll
                for (int jj = 0; jj < 4; ++jj)
                    bvr[jj] = (n0 + c4 + jj < N) ? p[jj] : 0.0f;
            }
        } else {
            const float* Bb = B + (size_t)pB * plane;
            int r = tid >> 2, c4 = (tid & 3) * 4;
            int gp = n0 + r;
            if (nFull || gp < N) {
                float4 t = *(const float4*)(Bb + (size_t)gp * ldb + koff + c4);
                bvr[0]=t.x; bvr[1]=t.y; bvr[2]=t.z; bvr[3]=t.w;
            } else { bvr[0]=bvr[1]=bvr[2]=bvr[3]=0.0f; }
        }
    };
    auto storeB = [&]() {
        if (TB == 0) {
            int r = tid >> 4, c4 = (tid & 15) * 4;
            #pragma unroll
            for (int q = 0; q < 4; ++q) Bs[r][c4+q] = bvr[q];
        } else {
            int r = tid >> 2, c4 = (tid & 3) * 4;
            #pragma unroll
            for (int q = 0; q < 4; ++q) Bs[c4+q][r] = bvr[q];
        }
    };

    if (kBeg < kEnd) {
        loadA(kBeg); loadB(kBeg);
        for (int k0 = kBeg; k0 < kEnd; k0 += 16) {
            storeA(); storeB();
            __syncthreads();
            if (k0 + 16 < kEnd) { loadA(k0 + 16); loadB(k0 + 16); }
            #pragma unroll
            for (int kk = 0; kk < 16; ++kk) {
                float a[4], bb[4];
                *(float4*)a  = *(const float4*)&As[kk][ty*4];
                *(float4*)bb = *(const float4*)&Bs[kk][tx*4];
                #pragma unroll
                for (int i = 0; i < 4; ++i)
                    #pragma unroll
                    for (int j = 0; j < 4; ++j)
                        acc[i][j] += a[i] * bb[j];
            }
            __syncthreads();
        }
    }

    #pragma unroll
    for (int i = 0; i < 4; ++i) {
        int gm = m0 + ty*4 + i;
        if (gm >= M) continue;
        #pragma unroll
        for (int j = 0; j < 4; ++j) {
            int gn = n0 + tx*4 + j;
            if (gn >= N) continue;
            C[(size_t)gm * ldc + gn] = acc[i][j];
        }
    }
}

// ---------------------------------------------------------------------------
// combine kernels
// ---------------------------------------------------------------------------
__global__ void combine_add2(const float* __restrict__ p0, float* __restrict__ o,
                             long stride) {
    int i = blockIdx.x * 256 + threadIdx.x;   // float4 elements
    float4 x = ((const float4*)p0)[i];
    float4 y = ((const float4*)(p0 + stride))[i];
    float4 r; r.x=x.x+y.x; r.y=x.y+y.y; r.z=x.z+y.z; r.w=x.w+y.w;
    ((float4*)o)[i] = r;
}

__global__ void combine_solm4(const float* __restrict__ p, float* __restrict__ o) {
    int i = blockIdx.x * 256 + threadIdx.x;   // 73728 elems -> 288 WGs
    o[i] = p[i] + p[i + 73728] + p[i + 2*73728] + p[i + 3*73728];
}

__global__ void combine_prior4(const float* __restrict__ p0,
                               const float* __restrict__ xin,
                               const float* __restrict__ W2g,
                               float* __restrict__ o, long stride) {
    __shared__ float w[16];
    int tid = threadIdx.x;
    if (tid < 16) w[tid] = W2g[tid];
    __syncthreads();
    int idx = blockIdx.x * 256 + tid;           // over 4*N2
    int b = idx / N2;
    int rem = idx - b * N2;
    int m = rem / NPTS, n = rem - m * NPTS;
    const float* xb = xin + (size_t)b * NPTS * 2;
    float r0 = xb[m*2+0] - xb[n*2+0];
    float r1 = xb[m*2+1] - xb[n*2+1];
    float u = (r0*r0 + r1*r1) * INVL2;
    float Kv = expf(-0.5f * u);
    float i2 = INVL2 * INVL2;
    float gK0 = r0 * INVL2 * Kv;
    float gK1 = r1 * INVL2 * Kv;
    float lapK = (u - 2.0f) * INVL2 * Kv;
    float gg00 = (INVL2 - r0*r0*i2) * Kv;
    float gg01 = (-r0*r1*i2) * Kv;
    float gg11 = (INVL2 - r1*r1*i2) * Kv;
    float gl0 = r0 * i2 * (4.0f - u) * Kv;
    float gl1 = r1 * i2 * (4.0f - u) * Kv;
    float ll = ((u-2.0f)*(u-2.0f) - 4.0f*u + 4.0f) * i2 * Kv;
    float prior =
          w[0]*Kv + w[1]*gK0 + w[2]*gK1 + w[3]*lapK
        + w[4]*(-gK0) + w[5]*gg00 + w[6]*gg01 + w[7]*gl0
        + w[8]*(-gK1) + w[9]*gg01 + w[10]*gg11 + w[11]*gl1
        + w[12]*lapK + w[13]*(-gl0) + w[14]*(-gl1) + w[15]*ll;
    float v = p0[idx] + p0[idx + stride] + p0[idx + 2*stride] + p0[idx + 3*stride]
            + prior;
    if (m == n) v += 1.1e-4f;
    o[idx] = v;
}

// ---------------------------------------------------------------------------
// opiKW2[b][i] = sum_j W2[i][j] * opiK[b][j]  — safe in-place (per-element)
// ---------------------------------------------------------------------------
__global__ void opiw2_k(const float* __restrict__ opiK, const float* __restrict__ W2,
                        float* __restrict__ outB) {
    int idx = blockIdx.x * 256 + threadIdx.x;
    int b = idx / N2;
    int rem = idx - b * N2;
    size_t base = (size_t)b * 4 * N2 + rem;
    float k0 = opiK[base], k1 = opiK[base + N2], k2 = opiK[base + 2*N2], k3 = opiK[base + 3*N2];
    #pragma unroll
    for (int i = 0; i < 4; ++i)
        outB[base + (size_t)i * N2] = W2[i*4+0]*k0 + W2[i*4+1]*k1 + W2[i*4+2]*k2 + W2[i*4+3]*k3;
}

// ---------------------------------------------------------------------------
__global__ __launch_bounds__(256)
void amean_k(const float* __restrict__ opimean, const float* __restrict__ weight,
             const float* __restrict__ bias, float* __restrict__ out) {
    int b = blockIdx.y;
    int m0 = blockIdx.x * 32;
    __shared__ float Wl[64][128];
    __shared__ float om[32][128];
    int tid = threadIdx.x;
    for (int idx = tid; idx < 64*128; idx += 256) Wl[idx / 128][idx & 127] = weight[idx];
    for (int idx = tid; idx < 32*128; idx += 256) {
        int m = idx >> 7, ck = idx & 127, c = ck >> 2, kop = ck & 3;
        om[m][ck] = opimean[((size_t)b * 4 + kop) * NPTS * 32 + (size_t)(m0 + m) * 32 + c];
    }
    __syncthreads();
    int ml = tid >> 3, o0 = (tid & 7) * 8;
    float acc[8] = {};
    for (int ck = 0; ck < 128; ++ck) {
        float v = om[ml][ck];
        #pragma unroll
        for (int q = 0; q < 8; ++q) acc[q] += v * Wl[o0+q][ck];
    }
    #pragma unroll
    for (int q = 0; q < 8; ++q)
        out[4608 + ((size_t)b * NPTS + m0 + ml) * 64 + o0 + q] = acc[q] + bias[o0+q];
}

// ---------------------------------------------------------------------------
static inline int gridSwz(int MT, int Z) { return 8 * 9 * ((MT * Z + 7) / 8); }
static inline int gridSwz2(int MT, int NX, int Z) { return 8 * NX * ((MT * Z + 7) / 8); }

extern "C" void kernel_launch(void* const* d_in, const int* in_sizes, int n_in,
                              void* d_out, int out_size, void* d_ws, size_t ws_size,
                              hipStream_t stream) {
    const float* xin    = (const float*)d_in[0];
    const float* meanin = (const float*)d_in[1];
    const float* Kin    = (const float*)d_in[2];
    const float* weight = (const float*)d_in[3];
    const float* bias   = (const float*)d_in[4];
    float* out = (float*)d_out;
    float* ws  = (float*)d_ws;

    const long N2L = N2;
    float* W2      = ws;                       // 16 (pad 64)
    float* LinvKK  = ws + 64;                  // 4*9*4096
    float* R1 = LinvKK + 147456;               // 4*N2: Kxx/A; later iW (Kin@Kinv)
    float* R2 = R1 + 4*N2L;                    // 4*N2: Linv; later solm/opim
    float* R3 = R2 + 4*N2L;                    // 4*N2: L panels; later Kinv
    float* R4 = R3 + 4*N2L;                    // 16*N2: opiK; later opiKW2 (in-place)
    float* R5 = R4 + 16*N2L;                   // 16*N2: Kinv partials; KiO; final partials
    float* R6 = R5 + 16*N2L;                   // 16*N2: solm partials; KiO sp1; H'

    // zero Linv (upper triangle must be 0)
    hipMemsetAsync(R2, 0, (size_t)4 * N2 * sizeof(float), stream);
    copy_xout<<<dim3(18), dim3(256), 0, stream>>>(xin, out);
    build_k<<<dim3((BSZ*N2)/256), dim3(256), 0, stream>>>(xin, R1, R4);
    w2_k<<<dim3(1), dim3(256), 0, stream>>>(weight, W2);
    // Cholesky: 9 launches. L panels -> R3; diag inverses -> LinvKK
    chol_diag0<<<dim3(BSZ), dim3(256), 0, stream>>>(R1, LinvKK);
    for (int kb = 0; kb < NT - 1; ++kb) {
        int t = NT - 1 - kb;
        chol_step<<<dim3(t*(t+1)/2, BSZ), dim3(256), 0, stream>>>(R1, R3, LinvKK, kb);
    }
    // triangular inverse -> R2
    trinv_blk<<<dim3(4, NT, BSZ), dim3(256), 0, stream>>>(R3, LinvKK, R2);
    // Kinv = Linv^T @ Linv  (SK2+tri, swizzled; partials -> R5; combine -> R3)
    mm_kernel<1,0,2,1,1,0><<<dim3(gridSwz(9,8)), dim3(256), 0, stream>>>(
        R2, R2, R5, 576,576,576,576, 576,576,576,
        N2L,N2L,N2L, 0,0, 4*N2L, 9);
    combine_add2<<<dim3(1296), dim3(256), 0, stream>>>(R5, R3, 4*N2L);
    // sol_mean = Kinv @ meanin  (SK4 partials -> R6; combine -> R2)
    mm_kernel<0,0,4,0,0,0><<<dim3(1,9,16), dim3(256), 0, stream>>>(
        R3, meanin, R6, 576,32,576,576, 576,32,32,
        N2L,18432,18432, 0,0, 73728, 9);
    combine_solm4<<<dim3(288), dim3(256), 0, stream>>>(R6, R2);
    // opimean = opiK @ sol_mean -> R2+73728
    mm_kernel<0,0,1,0,0,0><<<dim3(1,36,BSZ), dim3(256), 0, stream>>>(
        R4, R2, R2 + 73728, 2304,32,576,576, 576,32,32,
        4*N2L,18432,73728, 0,0, 0, 9);
    amean_k<<<dim3(18,BSZ), dim3(256), 0, stream>>>(R2 + 73728, weight, bias, out);
    // iW = Kin @ Kinv  (SK1, swizzled) -> R1  (-I folded into H' B-load)
    mm_kernel<0,0,1,0,1,0><<<dim3(gridSwz(9,4)), dim3(256), 0, stream>>>(
        Kin, R3, R1, 576,576,576,576, 576,576,576,
        N2L,N2L,N2L, 0,0, 0, 9);
    // KiO = opiK @ Kinv  (mm128, SK2: sp0 -> R5, sp1 -> R6; combine in-place R5)
    mm128<0,2,0><<<dim3(gridSwz2(18,5,8)), dim3(256), 0, stream>>>(
        R4, R3, R5, 2304,576,576,576, 576,576,576,
        4*N2L, N2L, 4*N2L, 0,0, 16*N2L, 18, 5);
    combine_add2<<<dim3(5184), dim3(256), 0, stream>>>(R5, R5, 16*N2L);
    // opiKW2 in-place on R4 (opiK no longer needed)
    opiw2_k<<<dim3((BSZ*N2)/256), dim3(256), 0, stream>>>(R4, W2, R4);
    // H' = KiO @ (iW - I)  (mm128, SK1, -I fold) -> R6
    mm128<0,1,1><<<dim3(gridSwz2(18,5,4)), dim3(256), 0, stream>>>(
        R5, R1, R6, 2304,576,576,576, 576,576,576,
        4*N2L, N2L, 4*N2L, 0,0, 0, 18, 5);
    // final AKA partial GEMM (mm128, TB=1, SK4): partials -> R5 (KiO dead)
    mm128<1,4,0><<<dim3(gridSwz2(5,5,16)), dim3(256), 0, stream>>>(
        R6, R4, R5, 576,576,2304,576, 576,576,576,
        4*N2L, 4*N2L, N2L, N2L,N2L, 4*N2L, 5, 5);
    // output 2: combine 4 partials + analytic prior + jitter
    combine_prior4<<<dim3(5184), dim3(256), 0, stream>>>(
        R5, xin, W2, out + 152064, 4*N2L);
}

// Round 11
// 1303.831 us; speedup vs baseline: 1.1229x; 1.1132x over previous
//
#include <hip/hip_runtime.h>
#include <math.h>

#define NPTS 576
#define N2 331776           // 576*576
#define BSZ 4
#define NB 64               // cholesky block
#define NT 9                // 576/64

#define INVL2 (1.0f/0.29311396f)

// ---------------------------------------------------------------------------
__global__ void copy_xout(const float* __restrict__ xin, float* __restrict__ out) {
    int idx = blockIdx.x * 256 + threadIdx.x;   // 18*256 = 4608 exact
    out[idx] = xin[idx];
}

// ---------------------------------------------------------------------------
// build Kxx (+jitter) and opiK (4 planes) from xin
// ---------------------------------------------------------------------------
__global__ void build_k(const float* __restrict__ xin,
                        float* __restrict__ Kxx, float* __restrict__ opiK) {
    int idx = blockIdx.x * 256 + threadIdx.x;
    int b = idx / N2;
    int rem = idx - b * N2;
    int m = rem / NPTS;
    int nn = rem - m * NPTS;
    const float* xb = xin + (size_t)b * NPTS * 2;
    float xm0 = xb[m*2],  xm1 = xb[m*2+1];
    float xn0 = xb[nn*2], xn1 = xb[nn*2+1];
    float r0 = xm0 - xn0, r1 = xm1 - xn1;
    float u = (r0*r0 + r1*r1) * INVL2;
    float Kv = expf(-0.5f * u);
    Kxx[idx] = Kv + ((m == nn) ? 1e-5f : 0.0f);
    size_t base = (size_t)b * 4 * N2 + rem;
    opiK[base]          = Kv;
    opiK[base + N2]     = -r0 * INVL2 * Kv;
    opiK[base + 2*N2]   = -r1 * INVL2 * Kv;
    opiK[base + 3*N2]   = (u - 2.0f) * INVL2 * Kv;
}

// ---------------------------------------------------------------------------
__global__ void w2_k(const float* __restrict__ w, float* __restrict__ W2) {
    __shared__ float red[256];
    int tid = threadIdx.x;
    int pair = tid & 15;
    int slice = tid >> 4;
    int i = pair >> 2, j = pair & 3;
    float s = 0.0f;
    for (int o = slice * 4; o < slice * 4 + 4; ++o)
        for (int c = 0; c < 32; ++c)
            s += w[o*128 + c*4 + i] * w[o*128 + c*4 + j];
    red[tid] = s;
    __syncthreads();
    if (tid < 16) {
        float t = 0.0f;
        #pragma unroll
        for (int k = 0; k < 16; ++k) t += red[pair + 16*k];
        W2[pair] = t * (1.0f/64.0f);
    }
}

// ---------------------------------------------------------------------------
// factor 64x64 SPD block in T (lower), produce V = T^{-1} (lower).
// Panel-blocked: in-wave 16-col panel factor + 16-rank SYRK per panel.
// ---------------------------------------------------------------------------
__device__ void factor_invert_64(float (*T)[NB+1], float (*V)[NB+1],
                                 float (*tmp)[17], int tid) {
    for (int p = 0; p < 4; ++p) {
        int cp = p * 16;
        if (tid < 64) {
            int r = tid;
            #pragma unroll 1
            for (int j = 0; j < 16; ++j) {
                int col = cp + j;
                if (r == col) T[col][col] = sqrtf(fmaxf(T[col][col], 1e-12f));
                float d = T[col][col];
                float lr = 0.0f;
                if (r > col) { lr = T[r][col] / d; T[r][col] = lr; }
                #pragma unroll 1
                for (int c = col + 1; c < cp + 16; ++c) {
                    float lc = T[c][col];
                    if (r >= c) T[r][c] -= lr * lc;
                }
            }
        }
        __syncthreads();
        int tr = 48 - cp;
        if (tr > 0) {
            for (int idx = tid; idx < tr * tr; idx += 256) {
                int r = cp + 16 + idx / tr;
                int c = cp + 16 + idx % tr;
                if (c <= r) {
                    float s = 0.0f;
                    #pragma unroll
                    for (int k = 0; k < 16; ++k) s += T[r][cp+k] * T[c][cp+k];
                    T[r][c] -= s;
                }
            }
        }
        __syncthreads();
    }
    if (tid < 64) {
        int I = tid >> 4, c = tid & 15, base = I * 16;
        for (int i = c; i < 16; ++i) {
            float s = (i == c) ? 1.0f : 0.0f;
            for (int k = c; k < i; ++k) s -= T[base+i][base+k] * V[base+k][base+c];
            V[base+i][base+c] = s / T[base+i][base+i];
        }
    }
    __syncthreads();
    const int PI[6] = {1,2,3,2,3,3};
    const int PJ[6] = {0,1,2,0,1,0};
    int rr16 = tid >> 4, cc16 = tid & 15;
    for (int p = 0; p < 6; ++p) {
        int I = PI[p], J = PJ[p];
        float s = 0.0f;
        for (int K = J; K < I; ++K)
            #pragma unroll
            for (int t = 0; t < 16; ++t)
                s += T[I*16+rr16][K*16+t] * V[K*16+t][J*16+cc16];
        tmp[rr16][cc16] = s;
        __syncthreads();
        float s2 = 0.0f;
        for (int t = 0; t <= rr16; ++t) s2 += V[I*16+rr16][I*16+t] * tmp[t][cc16];
        __syncthreads();
        V[I*16+rr16][J*16+cc16] = -s2;
        __syncthreads();
    }
}

// ---------------------------------------------------------------------------
__global__ void chol_diag0(const float* __restrict__ A, float* __restrict__ LinvKK) {
    int b = blockIdx.x;
    const float* Ab = A + (size_t)b * N2;
    __shared__ float T[NB][NB+1];
    __shared__ float V[NB][NB+1];
    __shared__ float tmp[16][17];
    int tid = threadIdx.x;
    for (int idx = tid; idx < NB*NB; idx += 256) {
        int r = idx >> 6, c = idx & 63;
        T[r][c] = Ab[(size_t)r * NPTS + c];
        V[r][c] = 0.0f;
    }
    __syncthreads();
    factor_invert_64(T, V, tmp, tid);
    float* Vg = LinvKK + (size_t)b * NT * NB * NB;
    for (int idx = tid; idx < NB*NB; idx += 256) Vg[idx] = V[idx >> 6][idx & 63];
}

// ---------------------------------------------------------------------------
// fused Cholesky step for panel kb. 9 total launches.
// ---------------------------------------------------------------------------
__global__ __launch_bounds__(256)
void chol_step(float* __restrict__ A, float* __restrict__ LL,
               float* __restrict__ LinvKK, int kb) {
    int b = blockIdx.y;
    int p = blockIdx.x;
    int ir = 0;
    while (p >= ir + 1) { p -= ir + 1; ir++; }
    int ib = kb + 1 + ir, jb = kb + 1 + p;
    float* Ab = A + (size_t)b * N2;
    float* LLb = LL + (size_t)b * N2;
    __shared__ float Ai[NB][NB+1];
    __shared__ float Aj[NB][NB+1];
    __shared__ float Vs[NB][NB+1];
    __shared__ float tmp[16][17];
    int tid = threadIdx.x;
    int tx = tid & 15, ty = tid >> 4;
    const float* Vg = LinvKK + ((size_t)b * NT + kb) * NB * NB;
    bool diag = (ib == jb);
    for (int idx = tid; idx < NB*NB; idx += 256) {
        int r = idx >> 6, c = idx & 63;
        Ai[r][c] = Ab[(size_t)(ib*NB + r) * NPTS + kb*NB + c];
        Aj[r][c] = diag ? 0.0f : Ab[(size_t)(jb*NB + r) * NPTS + kb*NB + c];
        Vs[r][c] = Vg[idx];
    }
    float U[4][4];
    #pragma unroll
    for (int i = 0; i < 4; ++i)
        #pragma unroll
        for (int j = 0; j < 4; ++j)
            U[i][j] = Ab[(size_t)(ib*NB + ty*4+i) * NPTS + jb*NB + tx*4+j];
    __syncthreads();
    float Li[4][4] = {}, Lj[4][4] = {};
    for (int k = 0; k < NB; ++k) {
        float a[4], v[4];
        #pragma unroll
        for (int i = 0; i < 4; ++i) a[i] = Ai[ty*4+i][k];
        #pragma unroll
        for (int j = 0; j < 4; ++j) v[j] = Vs[tx*4+j][k];
        #pragma unroll
        for (int i = 0; i < 4; ++i)
            #pragma unroll
            for (int j = 0; j < 4; ++j) Li[i][j] += a[i] * v[j];
        if (!diag) {
            float aj[4];
            #pragma unroll
            for (int i = 0; i < 4; ++i) aj[i] = Aj[ty*4+i][k];
            #pragma unroll
            for (int i = 0; i < 4; ++i)
                #pragma unroll
                for (int j = 0; j < 4; ++j) Lj[i][j] += aj[i] * v[j];
        }
    }
    __syncthreads();
    #pragma unroll
    for (int i = 0; i < 4; ++i)
        #pragma unroll
        for (int j = 0; j < 4; ++j) {
            Ai[ty*4+i][tx*4+j] = Li[i][j];
            Aj[ty*4+i][tx*4+j] = diag ? Li[i][j] : Lj[i][j];
        }
    if (diag) {
        #pragma unroll
        for (int i = 0; i < 4; ++i)
            #pragma unroll
            for (int j = 0; j < 4; ++j)
                LLb[(size_t)(ib*NB + ty*4+i) * NPTS + kb*NB + tx*4+j] = Li[i][j];
    }
    __syncthreads();
    float s[4][4] = {};
    for (int k = 0; k < NB; ++k) {
        float a[4], v[4];
        #pragma unroll
        for (int i = 0; i < 4; ++i) a[i] = Ai[ty*4+i][k];
        #pragma unroll
        for (int j = 0; j < 4; ++j) v[j] = Aj[tx*4+j][k];
        #pragma unroll
        for (int i = 0; i < 4; ++i)
            #pragma unroll
            for (int j = 0; j < 4; ++j) s[i][j] += a[i] * v[j];
    }
    #pragma unroll
    for (int i = 0; i < 4; ++i)
        #pragma unroll
        for (int j = 0; j < 4; ++j) U[i][j] -= s[i][j];
    if (blockIdx.x != 0) {
        #pragma unroll
        for (int i = 0; i < 4; ++i)
            #pragma unroll
            for (int j = 0; j < 4; ++j)
                Ab[(size_t)(ib*NB + ty*4+i) * NPTS + jb*NB + tx*4+j] = U[i][j];
        return;
    }
    __syncthreads();
    #pragma unroll
    for (int i = 0; i < 4; ++i)
        #pragma unroll
        for (int j = 0; j < 4; ++j) Ai[ty*4+i][tx*4+j] = U[i][j];
    for (int idx = tid; idx < NB*NB; idx += 256) Aj[idx >> 6][idx & 63] = 0.0f;
    __syncthreads();
    factor_invert_64(Ai, Aj, tmp, tid);
    float* Vo = LinvKK + ((size_t)b * NT + (kb + 1)) * NB * NB;
    for (int idx = tid; idx < NB*NB; idx += 256) Vo[idx] = Aj[idx >> 6][idx & 63];
}

// ---------------------------------------------------------------------------
// blocked triangular inverse. grid (4 col-splits, 9 block-cols, 4 batch)
// ---------------------------------------------------------------------------
__global__ __launch_bounds__(256)
void trinv_blk(const float* __restrict__ L, const float* __restrict__ LinvKK,
               float* __restrict__ Linv) {
    int sp = blockIdx.x, jb = blockIdx.y, b = blockIdx.z;
    const float* Lb = L + (size_t)b * N2;
    float* Xg = Linv + (size_t)b * N2;
    const float* Vg = LinvKK + (size_t)b * NT * NB * NB;
    int c0 = jb * NB + sp * 16;

    __shared__ float LsT[64][72];
    __shared__ float Xc[576][17];
    __shared__ float Ss[64][17];

    int tid = threadIdx.x;
    int tx = tid & 15, ty = tid >> 4;

    {
        const float* Vjj = Vg + (size_t)jb * NB * NB;
        int r = tid >> 2, c4 = (tid & 3) * 4;
        float4 v = *(const float4*)(Vjj + r * NB + sp * 16 + c4);
        Xc[r][c4+0] = v.x; Xc[r][c4+1] = v.y; Xc[r][c4+2] = v.z; Xc[r][c4+3] = v.w;
        *(float4*)(Xg + (size_t)(jb * NB + r) * NPTS + c0 + c4) = v;
    }
    __syncthreads();

    for (int ib = jb + 1; ib < NT; ++ib) {
        float acc[4] = {};
        for (int kb = jb; kb < ib; ++kb) {
            {
                int r = tid >> 2, t0 = (tid & 3) * 16;
                const float* src = Lb + (size_t)(ib * NB + r) * NPTS + kb * NB + t0;
                #pragma unroll
                for (int q = 0; q < 4; ++q) {
                    float4 v = *(const float4*)(src + q * 4);
                    LsT[t0 + q*4 + 0][r] = v.x;
                    LsT[t0 + q*4 + 1][r] = v.y;
                    LsT[t0 + q*4 + 2][r] = v.z;
                    LsT[t0 + q*4 + 3][r] = v.w;
                }
            }
            __syncthreads();
            int xbase = (kb - jb) * 64;
            #pragma unroll 8
            for (int t = 0; t < 64; ++t) {
                float a4[4]; *(float4*)a4 = *(const float4*)&LsT[t][ty*4];
                float xv = Xc[xbase + t][tx];
                #pragma unroll
                for (int i = 0; i < 4; ++i) acc[i] += a4[i] * xv;
            }
            __syncthreads();
        }
        #pragma unroll
        for (int i = 0; i < 4; ++i) Ss[ty*4+i][tx] = acc[i];
        {
            const float* Vii = Vg + (size_t)ib * NB * NB;
            int r = tid >> 2, t0 = (tid & 3) * 16;
            #pragma unroll
            for (int q = 0; q < 4; ++q) {
                float4 v = *(const float4*)(Vii + r * NB + t0 + q * 4);
                LsT[t0 + q*4 + 0][r] = v.x;
                LsT[t0 + q*4 + 1][r] = v.y;
                LsT[t0 + q*4 + 2][r] = v.z;
                LsT[t0 + q*4 + 3][r] = v.w;
            }
        }
        __syncthreads();
        float acc2[4] = {};
        #pragma unroll 8
        for (int t = 0; t < 64; ++t) {
            float a4[4]; *(float4*)a4 = *(const float4*)&LsT[t][ty*4];
            float sv = Ss[t][tx];
            #pragma unroll
            for (int i = 0; i < 4; ++i) acc2[i] += a4[i] * sv;
        }
        int obase = (ib - jb) * 64;
        #pragma unroll
        for (int i = 0; i < 4; ++i) {
            float v = -acc2[i];
            Xc[obase + ty*4 + i][tx] = v;
            Xg[(size_t)(ib * NB + ty*4 + i) * NPTS + c0 + tx] = v;
        }
        __syncthreads();
    }
}

// ---------------------------------------------------------------------------
// batched tiled matmul, 64x64 C-tile, 256 threads (4x4 micro), reg prefetch.
// TA=1: C=A^T B. TB=1: C=A B^T. SK-way K-split. TRI=1: skip k<max(m0,n0).
// SWZ=1: XCD-swizzled 1-D grid (NX=9). EPIB=1: B -= I on load (TB=0).
// TRIC=1: triangular C — grid.x enumerates lower tiles (my>=nx), grid.z=b*SK+sp.
// ---------------------------------------------------------------------------
template<int TA, int TB, int SK, int TRI, int SWZ, int EPIB, int TRIC>
__global__ __launch_bounds__(256)
void mm_kernel(const float* __restrict__ Aall, const float* __restrict__ Ball,
               float* __restrict__ Call,
               int M, int N, int K, int planeK,
               int lda, int ldb, int ldc,
               long sA, long sB, long sC, long pA, long pB, long sSplit, int MT)
{
    int nx, my, zz;
    if (TRIC) {
        int p = blockIdx.x;
        int ir = 0;
        while (p >= ir + 1) { p -= ir + 1; ir++; }
        my = ir; nx = p; zz = blockIdx.z;
    } else if (SWZ) {
        int id = blockIdx.x;
        int x8 = id & 7;
        int q  = id >> 3;
        nx = q % 9;
        int band = x8 + 8 * (q / 9);
        if (band >= MT * 4 * SK) return;
        my = band % MT;
        zz = band / MT;
    } else { nx = blockIdx.x; my = blockIdx.y; zz = blockIdx.z; }
    int sp = (SK > 1) ? (zz % SK) : 0;
    int b  = (SK > 1) ? (zz / SK) : zz;
    const float* A = Aall + (size_t)b * sA;
    const float* B = Ball + (size_t)b * sB;
    float* C = Call + (size_t)b * sC + (size_t)sp * sSplit;
    int n0 = nx * 64;
    int m0 = my * 64;

    __shared__ float As[16][68];
    __shared__ float Bs[16][68];

    int tid = threadIdx.x;
    int tx = tid & 15, ty = tid >> 4;

    float acc[4][4] = {};
    bool mFull = (m0 + 64 <= M);
    bool nFull = (n0 + 64 <= N);

    int triBeg = 0;
    if (TRI) { int mx = (m0 > n0 ? m0 : n0); triBeg = mx & ~15; }
    int kBeg = triBeg, kEnd = K;
    if (SK > 1) {
        int len = K - triBeg;
        int chunk = ((len / SK) + 15) & ~15;
        kBeg = triBeg + sp * chunk;
        if (kBeg > K) kBeg = K;
        kEnd = (sp == SK - 1) ? K : (kBeg + chunk < K ? kBeg + chunk : K);
    }

    float avr[4];
    float bvr[4];

    auto loadA = [&](int k0) {
        int plane = k0 / planeK;
        int koff  = k0 - plane * planeK;
        if (TA == 0) {
            const float* Ab = A + (size_t)pA * plane;
            int r = tid >> 2, c4 = (tid & 3) * 4;
            int gm = m0 + r;
            if (mFull || gm < M) {
                float4 t = *(const float4*)(Ab + (size_t)gm * lda + koff + c4);
                avr[0]=t.x; avr[1]=t.y; avr[2]=t.z; avr[3]=t.w;
            } else { avr[0]=avr[1]=avr[2]=avr[3]=0.0f; }
        } else {
            int r = tid >> 4, c4 = (tid & 15) * 4;
            const float* p = A + (size_t)(koff + r) * lda + m0 + c4;
            if (mFull) {
                float4 t = *(const float4*)p;
                avr[0]=t.x; avr[1]=t.y; avr[2]=t.z; avr[3]=t.w;
            } else {
                #pragma unroll
                for (int jj = 0; jj < 4; ++jj)
                    avr[jj] = (m0 + c4 + jj < M) ? p[jj] : 0.0f;
            }
        }
    };
    auto storeA = [&]() {
        if (TA == 0) {
            int r = tid >> 2, c4 = (tid & 3) * 4;
            #pragma unroll
            for (int q = 0; q < 4; ++q) As[c4+q][r] = avr[q];
        } else {
            int r = tid >> 4, c4 = (tid & 15) * 4;
            #pragma unroll
            for (int q = 0; q < 4; ++q) As[r][c4+q] = avr[q];
        }
    };
    auto loadB = [&](int k0) {
        int plane = k0 / planeK;
        int koff  = k0 - plane * planeK;
        if (TB == 0) {
            int r = tid >> 4, c4 = (tid & 15) * 4;
            const float* p = B + (size_t)(koff + r) * ldb + n0 + c4;
            if (nFull) {
                float4 t = *(const float4*)p;
                bvr[0]=t.x; bvr[1]=t.y; bvr[2]=t.z; bvr[3]=t.w;
            } else {
                #pragma unroll
                for (int jj = 0; jj < 4; ++jj)
                    bvr[jj] = (n0 + c4 + jj < N) ? p[jj] : 0.0f;
            }
            if (EPIB) {
                int gk = koff + r;
                #pragma unroll
                for (int jj = 0; jj < 4; ++jj)
                    if (gk == n0 + c4 + jj) bvr[jj] -= 1.0f;
            }
        } else {
            const float* Bb = B + (size_t)pB * plane;
            int r = tid >> 2, c4 = (tid & 3) * 4;
            int gp = n0 + r;
            if (nFull || gp < N) {
                float4 t = *(const float4*)(Bb + (size_t)gp * ldb + koff + c4);
                bvr[0]=t.x; bvr[1]=t.y; bvr[2]=t.z; bvr[3]=t.w;
            } else { bvr[0]=bvr[1]=bvr[2]=bvr[3]=0.0f; }
        }
    };
    auto storeB = [&]() {
        if (TB == 0) {
            int r = tid >> 4, c4 = (tid & 15) * 4;
            #pragma unroll
            for (int q = 0; q < 4; ++q) Bs[r][c4+q] = bvr[q];
        } else {
            int r = tid >> 2, c4 = (tid & 3) * 4;
            #pragma unroll
            for (int q = 0; q < 4; ++q) Bs[c4+q][r] = bvr[q];
        }
    };

    if (kBeg < kEnd) {
        loadA(kBeg); loadB(kBeg);
        for (int k0 = kBeg; k0 < kEnd; k0 += 16) {
            storeA(); storeB();
            __syncthreads();
            if (k0 + 16 < kEnd) { loadA(k0 + 16); loadB(k0 + 16); }
            #pragma unroll
            for (int kk = 0; kk < 16; ++kk) {
                float a[4], bb[4];
                *(float4*)a  = *(const float4*)&As[kk][ty*4];
                *(float4*)bb = *(const float4*)&Bs[kk][tx*4];
                #pragma unroll
                for (int i = 0; i < 4; ++i)
                    #pragma unroll
                    for (int j = 0; j < 4; ++j)
                        acc[i][j] += a[i] * bb[j];
            }
            __syncthreads();
        }
    }

    #pragma unroll
    for (int i = 0; i < 4; ++i) {
        int gm = m0 + ty*4 + i;
        if (gm >= M) continue;
        #pragma unroll
        for (int j = 0; j < 4; ++j) {
            int gn = n0 + tx*4 + j;
            if (gn >= N) continue;
            C[(size_t)gm * ldc + gn] = acc[i][j];
        }
    }
}

// ---------------------------------------------------------------------------
// combine kernels
// ---------------------------------------------------------------------------
__global__ void combine_add2(const float* __restrict__ p0, float* __restrict__ o,
                             long stride) {
    int i = blockIdx.x * 256 + threadIdx.x;   // float4 over 4*N2
    float4 x = ((const float4*)p0)[i];
    float4 y = ((const float4*)(p0 + stride))[i];
    float4 r; r.x=x.x+y.x; r.y=x.y+y.y; r.z=x.z+y.z; r.w=x.w+y.w;
    ((float4*)o)[i] = r;
}

__global__ void combine_solm4(const float* __restrict__ p, float* __restrict__ o) {
    int i = blockIdx.x * 256 + threadIdx.x;   // 73728 elems -> 288 WGs
    o[i] = p[i] + p[i + 73728] + p[i + 2*73728] + p[i + 3*73728];
}

// symmetric combine: partials valid only for m>=n; prior symmetric; write both
__global__ void combine_prior4_sym(const float* __restrict__ p0,
                                   const float* __restrict__ xin,
                                   const float* __restrict__ W2g,
                                   float* __restrict__ o, long stride) {
    __shared__ float w[16];
    int tid = threadIdx.x;
    if (tid < 16) w[tid] = W2g[tid];
    __syncthreads();
    int idx = blockIdx.x * 256 + tid;           // over 4*N2
    int b = idx / N2;
    int rem = idx - b * N2;
    int m = rem / NPTS, n = rem - m * NPTS;
    if (m < n) return;
    const float* xb = xin + (size_t)b * NPTS * 2;
    float r0 = xb[m*2+0] - xb[n*2+0];
    float r1 = xb[m*2+1] - xb[n*2+1];
    float u = (r0*r0 + r1*r1) * INVL2;
    float Kv = expf(-0.5f * u);
    float i2 = INVL2 * INVL2;
    float gK0 = r0 * INVL2 * Kv;
    float gK1 = r1 * INVL2 * Kv;
    float lapK = (u - 2.0f) * INVL2 * Kv;
    float gg00 = (INVL2 - r0*r0*i2) * Kv;
    float gg01 = (-r0*r1*i2) * Kv;
    float gg11 = (INVL2 - r1*r1*i2) * Kv;
    float gl0 = r0 * i2 * (4.0f - u) * Kv;
    float gl1 = r1 * i2 * (4.0f - u) * Kv;
    float ll = ((u-2.0f)*(u-2.0f) - 4.0f*u + 4.0f) * i2 * Kv;
    float prior =
          w[0]*Kv + w[1]*gK0 + w[2]*gK1 + w[3]*lapK
        + w[4]*(-gK0) + w[5]*gg00 + w[6]*gg01 + w[7]*gl0
        + w[8]*(-gK1) + w[9]*gg01 + w[10]*gg11 + w[11]*gl1
        + w[12]*lapK + w[13]*(-gl0) + w[14]*(-gl1) + w[15]*ll;
    float v = p0[idx] + p0[idx + stride] + p0[idx + 2*stride] + p0[idx + 3*stride]
            + prior;
    if (m == n) v += 1.1e-4f;
    o[(size_t)b * N2 + (size_t)m * NPTS + n] = v;
    if (m != n)
        o[(size_t)b * N2 + (size_t)n * NPTS + m] = v;
}

// ---------------------------------------------------------------------------
// opiKW2[b][i] = sum_j W2[i][j] * opiK[b][j]  — safe in-place (per-element)
// ---------------------------------------------------------------------------
__global__ void opiw2_k(const float* __restrict__ opiK, const float* __restrict__ W2,
                        float* __restrict__ outB) {
    int idx = blockIdx.x * 256 + threadIdx.x;
    int b = idx / N2;
    int rem = idx - b * N2;
    size_t base = (size_t)b * 4 * N2 + rem;
    float k0 = opiK[base], k1 = opiK[base + N2], k2 = opiK[base + 2*N2], k3 = opiK[base + 3*N2];
    #pragma unroll
    for (int i = 0; i < 4; ++i)
        outB[base + (size_t)i * N2] = W2[i*4+0]*k0 + W2[i*4+1]*k1 + W2[i*4+2]*k2 + W2[i*4+3]*k3;
}

// ---------------------------------------------------------------------------
__global__ __launch_bounds__(256)
void amean_k(const float* __restrict__ opimean, const float* __restrict__ weight,
             const float* __restrict__ bias, float* __restrict__ out) {
    int b = blockIdx.y;
    int m0 = blockIdx.x * 32;
    __shared__ float Wl[64][128];
    __shared__ float om[32][128];
    int tid = threadIdx.x;
    for (int idx = tid; idx < 64*128; idx += 256) Wl[idx / 128][idx & 127] = weight[idx];
    for (int idx = tid; idx < 32*128; idx += 256) {
        int m = idx >> 7, ck = idx & 127, c = ck >> 2, kop = ck & 3;
        om[m][ck] = opimean[((size_t)b * 4 + kop) * NPTS * 32 + (size_t)(m0 + m) * 32 + c];
    }
    __syncthreads();
    int ml = tid >> 3, o0 = (tid & 7) * 8;
    float acc[8] = {};
    for (int ck = 0; ck < 128; ++ck) {
        float v = om[ml][ck];
        #pragma unroll
        for (int q = 0; q < 8; ++q) acc[q] += v * Wl[o0+q][ck];
    }
    #pragma unroll
    for (int q = 0; q < 8; ++q)
        out[4608 + ((size_t)b * NPTS + m0 + ml) * 64 + o0 + q] = acc[q] + bias[o0+q];
}

// ---------------------------------------------------------------------------
static inline int gridSwz(int MT, int Z) { return 8 * 9 * ((MT * Z + 7) / 8); }

extern "C" void kernel_launch(void* const* d_in, const int* in_sizes, int n_in,
                              void* d_out, int out_size, void* d_ws, size_t ws_size,
                              hipStream_t stream) {
    const float* xin    = (const float*)d_in[0];
    const float* meanin = (const float*)d_in[1];
    const float* Kin    = (const float*)d_in[2];
    const float* weight = (const float*)d_in[3];
    const float* bias   = (const float*)d_in[4];
    float* out = (float*)d_out;
    float* ws  = (float*)d_ws;

    const long N2L = N2;
    float* W2      = ws;                       // 16 (pad 64)
    float* LinvKK  = ws + 64;                  // 4*9*4096
    float* R1 = LinvKK + 147456;               // 4*N2: Kxx/A; later iW (Kin@Kinv)
    float* R2 = R1 + 4*N2L;                    // 4*N2: Linv; later solm/opim
    float* R3 = R2 + 4*N2L;                    // 4*N2: L panels; later Kinv
    float* R4 = R3 + 4*N2L;                    // 16*N2: opiK; later opiKW2 (in-place)
    float* R5 = R4 + 16*N2L;                   // 16*N2: Kinv partials; KiO; final partials
    float* R6 = R5 + 16*N2L;                   // 16*N2: solm/iW partials; H'

    // zero Linv (upper triangle must be 0)
    hipMemsetAsync(R2, 0, (size_t)4 * N2 * sizeof(float), stream);
    copy_xout<<<dim3(18), dim3(256), 0, stream>>>(xin, out);
    build_k<<<dim3((BSZ*N2)/256), dim3(256), 0, stream>>>(xin, R1, R4);
    w2_k<<<dim3(1), dim3(256), 0, stream>>>(weight, W2);
    // Cholesky: 9 launches. L panels -> R3; diag inverses -> LinvKK
    chol_diag0<<<dim3(BSZ), dim3(256), 0, stream>>>(R1, LinvKK);
    for (int kb = 0; kb < NT - 1; ++kb) {
        int t = NT - 1 - kb;
        chol_step<<<dim3(t*(t+1)/2, BSZ), dim3(256), 0, stream>>>(R1, R3, LinvKK, kb);
    }
    // triangular inverse -> R2
    trinv_blk<<<dim3(4, NT, BSZ), dim3(256), 0, stream>>>(R3, LinvKK, R2);
    // Kinv = Linv^T @ Linv  (SK2+tri, swizzled; partials -> R5; combine -> R3)
    mm_kernel<1,0,2,1,1,0,0><<<dim3(gridSwz(9,8)), dim3(256), 0, stream>>>(
        R2, R2, R5, 576,576,576,576, 576,576,576,
        N2L,N2L,N2L, 0,0, 4*N2L, 9);
    combine_add2<<<dim3(1296), dim3(256), 0, stream>>>(R5, R3, 4*N2L);
    // sol_mean = Kinv @ meanin  (SK4 partials -> R6; combine -> R2)
    mm_kernel<0,0,4,0,0,0,0><<<dim3(1,9,16), dim3(256), 0, stream>>>(
        R3, meanin, R6, 576,32,576,576, 576,32,32,
        N2L,18432,18432, 0,0, 73728, 9);
    combine_solm4<<<dim3(288), dim3(256), 0, stream>>>(R6, R2);
    // opimean = opiK @ sol_mean -> R2+73728
    mm_kernel<0,0,1,0,0,0,0><<<dim3(1,36,BSZ), dim3(256), 0, stream>>>(
        R4, R2, R2 + 73728, 2304,32,576,576, 576,32,32,
        4*N2L,18432,73728, 0,0, 0, 9);
    amean_k<<<dim3(18,BSZ), dim3(256), 0, stream>>>(R2 + 73728, weight, bias, out);
    // iW = Kin @ Kinv  (SK2, swizzled; partials -> R6; combine -> R1)
    mm_kernel<0,0,2,0,1,0,0><<<dim3(gridSwz(9,8)), dim3(256), 0, stream>>>(
        Kin, R3, R6, 576,576,576,576, 576,576,576,
        N2L,N2L,N2L, 0,0, 4*N2L, 9);
    combine_add2<<<dim3(1296), dim3(256), 0, stream>>>(R6, R1, 4*N2L);
    // KiO = opiK @ Kinv  (swizzled) -> R5
    mm_kernel<0,0,1,0,1,0,0><<<dim3(gridSwz(36,4)), dim3(256), 0, stream>>>(
        R4, R3, R5, 2304,576,576,576, 576,576,576,
        4*N2L,N2L,4*N2L, 0,0, 0, 36);
    // opiKW2 in-place on R4 (opiK no longer needed)
    opiw2_k<<<dim3((BSZ*N2)/256), dim3(256), 0, stream>>>(R4, W2, R4);
    // H' = KiO @ (iW - I)  (swizzled, -I fold) -> R6
    mm_kernel<0,0,1,0,1,1,0><<<dim3(gridSwz(36,4)), dim3(256), 0, stream>>>(
        R5, R1, R6, 2304,576,576,576, 576,576,576,
        4*N2L,N2L,4*N2L, 0,0, 0, 36);
    // final AKA partial GEMM — SYMMETRIC: only 45 lower tiles (my>=nx), SK4.
    // partials -> R5 (sC=N2 batch plane, sSplit=4*N2 split plane)
    mm_kernel<0,1,4,0,0,0,1><<<dim3(45,1,BSZ*4), dim3(256), 0, stream>>>(
        R6, R4, R5, 576,576,2304,576, 576,576,576,
        4*N2L, 4*N2L, N2L, N2L,N2L, 4*N2L, 9);
    // output 2: combine 4 partials (m>=n) + analytic prior + jitter, mirrored
    combine_prior4_sym<<<dim3(5184), dim3(256), 0, stream>>>(
        R5, xin, W2, out + 152064, 4*N2L);
}

// Round 12
// 1241.209 us; speedup vs baseline: 1.1796x; 1.0505x over previous
//
#include <hip/hip_runtime.h>
#include <math.h>

#define NPTS 576
#define N2 331776           // 576*576
#define BSZ 4
#define NB 64               // cholesky block
#define NT 9                // 576/64

#define INVL2 (1.0f/0.29311396f)

// ---------------------------------------------------------------------------
__global__ void copy_xout(const float* __restrict__ xin, float* __restrict__ out) {
    int idx = blockIdx.x * 256 + threadIdx.x;   // 18*256 = 4608 exact
    out[idx] = xin[idx];
}

// ---------------------------------------------------------------------------
// build Kxx (+jitter) and opiK (4 planes) from xin
// ---------------------------------------------------------------------------
__global__ void build_k(const float* __restrict__ xin,
                        float* __restrict__ Kxx, float* __restrict__ opiK) {
    int idx = blockIdx.x * 256 + threadIdx.x;
    int b = idx / N2;
    int rem = idx - b * N2;
    int m = rem / NPTS;
    int nn = rem - m * NPTS;
    const float* xb = xin + (size_t)b * NPTS * 2;
    float xm0 = xb[m*2],  xm1 = xb[m*2+1];
    float xn0 = xb[nn*2], xn1 = xb[nn*2+1];
    float r0 = xm0 - xn0, r1 = xm1 - xn1;
    float u = (r0*r0 + r1*r1) * INVL2;
    float Kv = expf(-0.5f * u);
    Kxx[idx] = Kv + ((m == nn) ? 1e-5f : 0.0f);
    size_t base = (size_t)b * 4 * N2 + rem;
    opiK[base]          = Kv;
    opiK[base + N2]     = -r0 * INVL2 * Kv;
    opiK[base + 2*N2]   = -r1 * INVL2 * Kv;
    opiK[base + 3*N2]   = (u - 2.0f) * INVL2 * Kv;
}

// ---------------------------------------------------------------------------
__global__ void w2_k(const float* __restrict__ w, float* __restrict__ W2) {
    __shared__ float red[256];
    int tid = threadIdx.x;
    int pair = tid & 15;
    int slice = tid >> 4;
    int i = pair >> 2, j = pair & 3;
    float s = 0.0f;
    for (int o = slice * 4; o < slice * 4 + 4; ++o)
        for (int c = 0; c < 32; ++c)
            s += w[o*128 + c*4 + i] * w[o*128 + c*4 + j];
    red[tid] = s;
    __syncthreads();
    if (tid < 16) {
        float t = 0.0f;
        #pragma unroll
        for (int k = 0; k < 16; ++k) t += red[pair + 16*k];
        W2[pair] = t * (1.0f/64.0f);
    }
}

// ---------------------------------------------------------------------------
// factor 64x64 SPD block in T (lower), produce V = T^{-1} (lower).
// ---------------------------------------------------------------------------
__device__ void factor_invert_64(float (*T)[NB+1], float (*V)[NB+1],
                                 float (*tmp)[17], int tid) {
    for (int p = 0; p < 4; ++p) {
        int cp = p * 16;
        if (tid < 64) {
            int r = tid;
            #pragma unroll 1
            for (int j = 0; j < 16; ++j) {
                int col = cp + j;
                if (r == col) T[col][col] = sqrtf(fmaxf(T[col][col], 1e-12f));
                float d = T[col][col];
                float lr = 0.0f;
                if (r > col) { lr = T[r][col] / d; T[r][col] = lr; }
                #pragma unroll 1
                for (int c = col + 1; c < cp + 16; ++c) {
                    float lc = T[c][col];
                    if (r >= c) T[r][c] -= lr * lc;
                }
            }
        }
        __syncthreads();
        int tr = 48 - cp;
        if (tr > 0) {
            for (int idx = tid; idx < tr * tr; idx += 256) {
                int r = cp + 16 + idx / tr;
                int c = cp + 16 + idx % tr;
                if (c <= r) {
                    float s = 0.0f;
                    #pragma unroll
                    for (int k = 0; k < 16; ++k) s += T[r][cp+k] * T[c][cp+k];
                    T[r][c] -= s;
                }
            }
        }
        __syncthreads();
    }
    if (tid < 64) {
        int I = tid >> 4, c = tid & 15, base = I * 16;
        for (int i = c; i < 16; ++i) {
            float s = (i == c) ? 1.0f : 0.0f;
            for (int k = c; k < i; ++k) s -= T[base+i][base+k] * V[base+k][base+c];
            V[base+i][base+c] = s / T[base+i][base+i];
        }
    }
    __syncthreads();
    const int PI[6] = {1,2,3,2,3,3};
    const int PJ[6] = {0,1,2,0,1,0};
    int rr16 = tid >> 4, cc16 = tid & 15;
    for (int p = 0; p < 6; ++p) {
        int I = PI[p], J = PJ[p];
        float s = 0.0f;
        for (int K = J; K < I; ++K)
            #pragma unroll
            for (int t = 0; t < 16; ++t)
                s += T[I*16+rr16][K*16+t] * V[K*16+t][J*16+cc16];
        tmp[rr16][cc16] = s;
        __syncthreads();
        float s2 = 0.0f;
        for (int t = 0; t <= rr16; ++t) s2 += V[I*16+rr16][I*16+t] * tmp[t][cc16];
        __syncthreads();
        V[I*16+rr16][J*16+cc16] = -s2;
        __syncthreads();
    }
}

// ---------------------------------------------------------------------------
__global__ void chol_diag0(const float* __restrict__ A, float* __restrict__ LinvKK) {
    int b = blockIdx.x;
    const float* Ab = A + (size_t)b * N2;
    __shared__ float T[NB][NB+1];
    __shared__ float V[NB][NB+1];
    __shared__ float tmp[16][17];
    int tid = threadIdx.x;
    for (int idx = tid; idx < NB*NB; idx += 256) {
        int r = idx >> 6, c = idx & 63;
        T[r][c] = Ab[(size_t)r * NPTS + c];
        V[r][c] = 0.0f;
    }
    __syncthreads();
    factor_invert_64(T, V, tmp, tid);
    float* Vg = LinvKK + (size_t)b * NT * NB * NB;
    for (int idx = tid; idx < NB*NB; idx += 256) Vg[idx] = V[idx >> 6][idx & 63];
}

// ---------------------------------------------------------------------------
// fused Cholesky step for panel kb. 9 total launches.
// ---------------------------------------------------------------------------
__global__ __launch_bounds__(256)
void chol_step(float* __restrict__ A, float* __restrict__ LL,
               float* __restrict__ LinvKK, int kb) {
    int b = blockIdx.y;
    int p = blockIdx.x;
    int ir = 0;
    while (p >= ir + 1) { p -= ir + 1; ir++; }
    int ib = kb + 1 + ir, jb = kb + 1 + p;
    float* Ab = A + (size_t)b * N2;
    float* LLb = LL + (size_t)b * N2;
    __shared__ float Ai[NB][NB+1];
    __shared__ float Aj[NB][NB+1];
    __shared__ float Vs[NB][NB+1];
    __shared__ float tmp[16][17];
    int tid = threadIdx.x;
    int tx = tid & 15, ty = tid >> 4;
    const float* Vg = LinvKK + ((size_t)b * NT + kb) * NB * NB;
    bool diag = (ib == jb);
    for (int idx = tid; idx < NB*NB; idx += 256) {
        int r = idx >> 6, c = idx & 63;
        Ai[r][c] = Ab[(size_t)(ib*NB + r) * NPTS + kb*NB + c];
        Aj[r][c] = diag ? 0.0f : Ab[(size_t)(jb*NB + r) * NPTS + kb*NB + c];
        Vs[r][c] = Vg[idx];
    }
    float U[4][4];
    #pragma unroll
    for (int i = 0; i < 4; ++i)
        #pragma unroll
        for (int j = 0; j < 4; ++j)
            U[i][j] = Ab[(size_t)(ib*NB + ty*4+i) * NPTS + jb*NB + tx*4+j];
    __syncthreads();
    float Li[4][4] = {}, Lj[4][4] = {};
    for (int k = 0; k < NB; ++k) {
        float a[4], v[4];
        #pragma unroll
        for (int i = 0; i < 4; ++i) a[i] = Ai[ty*4+i][k];
        #pragma unroll
        for (int j = 0; j < 4; ++j) v[j] = Vs[tx*4+j][k];
        #pragma unroll
        for (int i = 0; i < 4; ++i)
            #pragma unroll
            for (int j = 0; j < 4; ++j) Li[i][j] += a[i] * v[j];
        if (!diag) {
            float aj[4];
            #pragma unroll
            for (int i = 0; i < 4; ++i) aj[i] = Aj[ty*4+i][k];
            #pragma unroll
            for (int i = 0; i < 4; ++i)
                #pragma unroll
                for (int j = 0; j < 4; ++j) Lj[i][j] += aj[i] * v[j];
        }
    }
    __syncthreads();
    #pragma unroll
    for (int i = 0; i < 4; ++i)
        #pragma unroll
        for (int j = 0; j < 4; ++j) {
            Ai[ty*4+i][tx*4+j] = Li[i][j];
            Aj[ty*4+i][tx*4+j] = diag ? Li[i][j] : Lj[i][j];
        }
    if (diag) {
        #pragma unroll
        for (int i = 0; i < 4; ++i)
            #pragma unroll
            for (int j = 0; j < 4; ++j)
                LLb[(size_t)(ib*NB + ty*4+i) * NPTS + kb*NB + tx*4+j] = Li[i][j];
    }
    __syncthreads();
    float s[4][4] = {};
    for (int k = 0; k < NB; ++k) {
        float a[4], v[4];
        #pragma unroll
        for (int i = 0; i < 4; ++i) a[i] = Ai[ty*4+i][k];
        #pragma unroll
        for (int j = 0; j < 4; ++j) v[j] = Aj[tx*4+j][k];
        #pragma unroll
        for (int i = 0; i < 4; ++i)
            #pragma unroll
            for (int j = 0; j < 4; ++j) s[i][j] += a[i] * v[j];
    }
    #pragma unroll
    for (int i = 0; i < 4; ++i)
        #pragma unroll
        for (int j = 0; j < 4; ++j) U[i][j] -= s[i][j];
    if (blockIdx.x != 0) {
        #pragma unroll
        for (int i = 0; i < 4; ++i)
            #pragma unroll
            for (int j = 0; j < 4; ++j)
                Ab[(size_t)(ib*NB + ty*4+i) * NPTS + jb*NB + tx*4+j] = U[i][j];
        return;
    }
    __syncthreads();
    #pragma unroll
    for (int i = 0; i < 4; ++i)
        #pragma unroll
        for (int j = 0; j < 4; ++j) Ai[ty*4+i][tx*4+j] = U[i][j];
    for (int idx = tid; idx < NB*NB; idx += 256) Aj[idx >> 6][idx & 63] = 0.0f;
    __syncthreads();
    factor_invert_64(Ai, Aj, tmp, tid);
    float* Vo = LinvKK + ((size_t)b * NT + (kb + 1)) * NB * NB;
    for (int idx = tid; idx < NB*NB; idx += 256) Vo[idx] = Aj[idx >> 6][idx & 63];
}

// ---------------------------------------------------------------------------
// blocked triangular inverse. grid (4 col-splits, 9 block-cols, 4 batch)
// ---------------------------------------------------------------------------
__global__ __launch_bounds__(256)
void trinv_blk(const float* __restrict__ L, const float* __restrict__ LinvKK,
               float* __restrict__ Linv) {
    int sp = blockIdx.x, jb = blockIdx.y, b = blockIdx.z;
    const float* Lb = L + (size_t)b * N2;
    float* Xg = Linv + (size_t)b * N2;
    const float* Vg = LinvKK + (size_t)b * NT * NB * NB;
    int c0 = jb * NB + sp * 16;

    __shared__ float LsT[64][72];
    __shared__ float Xc[576][17];
    __shared__ float Ss[64][17];

    int tid = threadIdx.x;
    int tx = tid & 15, ty = tid >> 4;

    {
        const float* Vjj = Vg + (size_t)jb * NB * NB;
        int r = tid >> 2, c4 = (tid & 3) * 4;
        float4 v = *(const float4*)(Vjj + r * NB + sp * 16 + c4);
        Xc[r][c4+0] = v.x; Xc[r][c4+1] = v.y; Xc[r][c4+2] = v.z; Xc[r][c4+3] = v.w;
        *(float4*)(Xg + (size_t)(jb * NB + r) * NPTS + c0 + c4) = v;
    }
    __syncthreads();

    for (int ib = jb + 1; ib < NT; ++ib) {
        float acc[4] = {};
        for (int kb = jb; kb < ib; ++kb) {
            {
                int r = tid >> 2, t0 = (tid & 3) * 16;
                const float* src = Lb + (size_t)(ib * NB + r) * NPTS + kb * NB + t0;
                #pragma unroll
                for (int q = 0; q < 4; ++q) {
                    float4 v = *(const float4*)(src + q * 4);
                    LsT[t0 + q*4 + 0][r] = v.x;
                    LsT[t0 + q*4 + 1][r] = v.y;
                    LsT[t0 + q*4 + 2][r] = v.z;
                    LsT[t0 + q*4 + 3][r] = v.w;
                }
            }
            __syncthreads();
            int xbase = (kb - jb) * 64;
            #pragma unroll 8
            for (int t = 0; t < 64; ++t) {
                float a4[4]; *(float4*)a4 = *(const float4*)&LsT[t][ty*4];
                float xv = Xc[xbase + t][tx];
                #pragma unroll
                for (int i = 0; i < 4; ++i) acc[i] += a4[i] * xv;
            }
            __syncthreads();
        }
        #pragma unroll
        for (int i = 0; i < 4; ++i) Ss[ty*4+i][tx] = acc[i];
        {
            const float* Vii = Vg + (size_t)ib * NB * NB;
            int r = tid >> 2, t0 = (tid & 3) * 16;
            #pragma unroll
            for (int q = 0; q < 4; ++q) {
                float4 v = *(const float4*)(Vii + r * NB + t0 + q * 4);
                LsT[t0 + q*4 + 0][r] = v.x;
                LsT[t0 + q*4 + 1][r] = v.y;
                LsT[t0 + q*4 + 2][r] = v.z;
                LsT[t0 + q*4 + 3][r] = v.w;
            }
        }
        __syncthreads();
        float acc2[4] = {};
        #pragma unroll 8
        for (int t = 0; t < 64; ++t) {
            float a4[4]; *(float4*)a4 = *(const float4*)&LsT[t][ty*4];
            float sv = Ss[t][tx];
            #pragma unroll
            for (int i = 0; i < 4; ++i) acc2[i] += a4[i] * sv;
        }
        int obase = (ib - jb) * 64;
        #pragma unroll
        for (int i = 0; i < 4; ++i) {
            float v = -acc2[i];
            Xc[obase + ty*4 + i][tx] = v;
            Xg[(size_t)(ib * NB + ty*4 + i) * NPTS + c0 + tx] = v;
        }
        __syncthreads();
    }
}

// ---------------------------------------------------------------------------
// mm_p2: plane-PAIR GEMM for C[p] = A[p] @ B (B shared across 4 planes).
// One WG computes the same 64x64 (m,n) tile for TWO planes: per kk,
// 3 ds_read_b128 feed 32 FMAs (10.7 MACs/instr vs 8 for plain 4x4).
// Fixed geometry M=N=K=576, lda=ldb=ldc=576, 4 planes as 2 pairs.
// SK-way K-split (chunk 288). EPIB=1: B -= I on load. XCD-swizzled grid.
// ---------------------------------------------------------------------------
template<int SK, int EPIB>
__global__ __launch_bounds__(256)
void mm_p2(const float* __restrict__ Aall, const float* __restrict__ Ball,
           float* __restrict__ Call, long sA, long sB, long sC, long sSplit)
{
    int id = blockIdx.x;
    int x8 = id & 7, qq = id >> 3;
    int nx = qq % 9;
    int band = x8 + 8 * (qq / 9);
    if (band >= 18 * BSZ * SK) return;
    int t  = band % 18;
    int zz = band / 18;
    int pp = t / 9, my = t % 9;
    int sp = (SK > 1) ? (zz % SK) : 0;
    int b  = (SK > 1) ? (zz / SK) : zz;
    const float* A0 = Aall + (size_t)b * sA + (size_t)(pp * 2) * N2;
    const float* A1 = A0 + N2;
    const float* B  = Ball + (size_t)b * sB;
    float* C0 = Call + (size_t)b * sC + (size_t)(pp * 2) * N2 + (size_t)sp * sSplit;
    float* C1 = C0 + N2;
    int n0 = nx * 64, m0 = my * 64;

    __shared__ float As[2][16][68];
    __shared__ float Bs[16][68];

    int tid = threadIdx.x;
    int tx = tid & 15, ty = tid >> 4;

    float acc[2][4][4] = {};

    int kBeg = 0, kEnd = 576;
    if (SK == 2) { kBeg = sp * 288; kEnd = kBeg + 288; }

    // A staging: 128 threads per plane; each loads 8 consecutive k of one m-row
    int pl = tid >> 7;
    int q2 = tid & 127;
    int am = q2 >> 1;
    int ak = (q2 & 1) * 8;
    const float* Apl = pl ? A1 : A0;
    // B staging
    int br = tid >> 4, bc = (tid & 15) * 4;

    float av[8], bv[4];
    auto loadA = [&](int k0) {
        const float* p = Apl + (size_t)(m0 + am) * 576 + k0 + ak;
        float4 t0 = *(const float4*)p;
        float4 t1 = *(const float4*)(p + 4);
        av[0]=t0.x; av[1]=t0.y; av[2]=t0.z; av[3]=t0.w;
        av[4]=t1.x; av[5]=t1.y; av[6]=t1.z; av[7]=t1.w;
    };
    auto storeA = [&]() {
        #pragma unroll
        for (int j = 0; j < 8; ++j) As[pl][ak + j][am] = av[j];
    };
    auto loadB = [&](int k0) {
        const float* p = B + (size_t)(k0 + br) * 576 + n0 + bc;
        float4 t4 = *(const float4*)p;
        bv[0]=t4.x; bv[1]=t4.y; bv[2]=t4.z; bv[3]=t4.w;
        if (EPIB) {
            int gk = k0 + br;
            #pragma unroll
            for (int jj = 0; jj < 4; ++jj)
                if (gk == n0 + bc + jj) bv[jj] -= 1.0f;
        }
    };
    auto storeB = [&]() {
        *(float4*)&Bs[br][bc] = *(float4*)bv;
    };

    loadA(kBeg); loadB(kBeg);
    for (int k0 = kBeg; k0 < kEnd; k0 += 16) {
        storeA(); storeB();
        __syncthreads();
        if (k0 + 16 < kEnd) { loadA(k0 + 16); loadB(k0 + 16); }
        #pragma unroll
        for (int kk = 0; kk < 16; ++kk) {
            float a0[4], a1[4], bb[4];
            *(float4*)a0 = *(const float4*)&As[0][kk][ty*4];
            *(float4*)a1 = *(const float4*)&As[1][kk][ty*4];
            *(float4*)bb = *(const float4*)&Bs[kk][tx*4];
            #pragma unroll
            for (int i = 0; i < 4; ++i)
                #pragma unroll
                for (int j = 0; j < 4; ++j) {
                    acc[0][i][j] += a0[i] * bb[j];
                    acc[1][i][j] += a1[i] * bb[j];
                }
        }
        __syncthreads();
    }

    #pragma unroll
    for (int i = 0; i < 4; ++i) {
        size_t rowoff = (size_t)(m0 + ty*4 + i) * 576 + n0 + tx*4;
        float4 v0, v1;
        v0.x=acc[0][i][0]; v0.y=acc[0][i][1]; v0.z=acc[0][i][2]; v0.w=acc[0][i][3];
        v1.x=acc[1][i][0]; v1.y=acc[1][i][1]; v1.z=acc[1][i][2]; v1.w=acc[1][i][3];
        *(float4*)(C0 + rowoff) = v0;
        *(float4*)(C1 + rowoff) = v1;
    }
}

// ---------------------------------------------------------------------------
// batched tiled matmul, 64x64 C-tile, 256 threads (4x4 micro), reg prefetch.
// TA=1: C=A^T B. TB=1: C=A B^T. SK-way K-split. TRI=1: skip k<max(m0,n0).
// SWZ=1: XCD-swizzled 1-D grid (NX=9). EPIB=1: B -= I on load (TB=0).
// TRIC=1: triangular C — grid.x enumerates lower tiles (my>=nx), grid.z=b*SK+sp.
// ---------------------------------------------------------------------------
template<int TA, int TB, int SK, int TRI, int SWZ, int EPIB, int TRIC>
__global__ __launch_bounds__(256)
void mm_kernel(const float* __restrict__ Aall, const float* __restrict__ Ball,
               float* __restrict__ Call,
               int M, int N, int K, int planeK,
               int lda, int ldb, int ldc,
               long sA, long sB, long sC, long pA, long pB, long sSplit, int MT)
{
    int nx, my, zz;
    if (TRIC) {
        int p = blockIdx.x;
        int ir = 0;
        while (p >= ir + 1) { p -= ir + 1; ir++; }
        my = ir; nx = p; zz = blockIdx.z;
    } else if (SWZ) {
        int id = blockIdx.x;
        int x8 = id & 7;
        int q  = id >> 3;
        nx = q % 9;
        int band = x8 + 8 * (q / 9);
        if (band >= MT * 4 * SK) return;
        my = band % MT;
        zz = band / MT;
    } else { nx = blockIdx.x; my = blockIdx.y; zz = blockIdx.z; }
    int sp = (SK > 1) ? (zz % SK) : 0;
    int b  = (SK > 1) ? (zz / SK) : zz;
    const float* A = Aall + (size_t)b * sA;
    const float* B = Ball + (size_t)b * sB;
    float* C = Call + (size_t)b * sC + (size_t)sp * sSplit;
    int n0 = nx * 64;
    int m0 = my * 64;

    __shared__ float As[16][68];
    __shared__ float Bs[16][68];

    int tid = threadIdx.x;
    int tx = tid & 15, ty = tid >> 4;

    float acc[4][4] = {};
    bool mFull = (m0 + 64 <= M);
    bool nFull = (n0 + 64 <= N);

    int triBeg = 0;
    if (TRI) { int mx = (m0 > n0 ? m0 : n0); triBeg = mx & ~15; }
    int kBeg = triBeg, kEnd = K;
    if (SK > 1) {
        int len = K - triBeg;
        int chunk = ((len / SK) + 15) & ~15;
        kBeg = triBeg + sp * chunk;
        if (kBeg > K) kBeg = K;
        kEnd = (sp == SK - 1) ? K : (kBeg + chunk < K ? kBeg + chunk : K);
    }

    float avr[4];
    float bvr[4];

    auto loadA = [&](int k0) {
        int plane = k0 / planeK;
        int koff  = k0 - plane * planeK;
        if (TA == 0) {
            const float* Ab = A + (size_t)pA * plane;
            int r = tid >> 2, c4 = (tid & 3) * 4;
            int gm = m0 + r;
            if (mFull || gm < M) {
                float4 t = *(const float4*)(Ab + (size_t)gm * lda + koff + c4);
                avr[0]=t.x; avr[1]=t.y; avr[2]=t.z; avr[3]=t.w;
            } else { avr[0]=avr[1]=avr[2]=avr[3]=0.0f; }
        } else {
            int r = tid >> 4, c4 = (tid & 15) * 4;
            const float* p = A + (size_t)(koff + r) * lda + m0 + c4;
            if (mFull) {
                float4 t = *(const float4*)p;
                avr[0]=t.x; avr[1]=t.y; avr[2]=t.z; avr[3]=t.w;
            } else {
                #pragma unroll
                for (int jj = 0; jj < 4; ++jj)
                    avr[jj] = (m0 + c4 + jj < M) ? p[jj] : 0.0f;
            }
        }
    };
    auto storeA = [&]() {
        if (TA == 0) {
            int r = tid >> 2, c4 = (tid & 3) * 4;
            #pragma unroll
            for (int q = 0; q < 4; ++q) As[c4+q][r] = avr[q];
        } else {
            int r = tid >> 4, c4 = (tid & 15) * 4;
            #pragma unroll
            for (int q = 0; q < 4; ++q) As[r][c4+q] = avr[q];
        }
    };
    auto loadB = [&](int k0) {
        int plane = k0 / planeK;
        int koff  = k0 - plane * planeK;
        if (TB == 0) {
            int r = tid >> 4, c4 = (tid & 15) * 4;
            const float* p = B + (size_t)(koff + r) * ldb + n0 + c4;
            if (nFull) {
                float4 t = *(const float4*)p;
                bvr[0]=t.x; bvr[1]=t.y; bvr[2]=t.z; bvr[3]=t.w;
            } else {
                #pragma unroll
                for (int jj = 0; jj < 4; ++jj)
                    bvr[jj] = (n0 + c4 + jj < N) ? p[jj] : 0.0f;
            }
            if (EPIB) {
                int gk = koff + r;
                #pragma unroll
                for (int jj = 0; jj < 4; ++jj)
                    if (gk == n0 + c4 + jj) bvr[jj] -= 1.0f;
            }
        } else {
            const float* Bb = B + (size_t)pB * plane;
            int r = tid >> 2, c4 = (tid & 3) * 4;
            int gp = n0 + r;
            if (nFull || gp < N) {
                float4 t = *(const float4*)(Bb + (size_t)gp * ldb + koff + c4);
                bvr[0]=t.x; bvr[1]=t.y; bvr[2]=t.z; bvr[3]=t.w;
            } else { bvr[0]=bvr[1]=bvr[2]=bvr[3]=0.0f; }
        }
    };
    auto storeB = [&]() {
        if (TB == 0) {
            int r = tid >> 4, c4 = (tid & 15) * 4;
            #pragma unroll
            for (int q = 0; q < 4; ++q) Bs[r][c4+q] = bvr[q];
        } else {
            int r = tid >> 2, c4 = (tid & 3) * 4;
            #pragma unroll
            for (int q = 0; q < 4; ++q) Bs[c4+q][r] = bvr[q];
        }
    };

    if (kBeg < kEnd) {
        loadA(kBeg); loadB(kBeg);
        for (int k0 = kBeg; k0 < kEnd; k0 += 16) {
            storeA(); storeB();
            __syncthreads();
            if (k0 + 16 < kEnd) { loadA(k0 + 16); loadB(k0 + 16); }
            #pragma unroll
            for (int kk = 0; kk < 16; ++kk) {
                float a[4], bb[4];
                *(float4*)a  = *(const float4*)&As[kk][ty*4];
                *(float4*)bb = *(const float4*)&Bs[kk][tx*4];
                #pragma unroll
                for (int i = 0; i < 4; ++i)
                    #pragma unroll
                    for (int j = 0; j < 4; ++j)
                        acc[i][j] += a[i] * bb[j];
            }
            __syncthreads();
        }
    }

    #pragma unroll
    for (int i = 0; i < 4; ++i) {
        int gm = m0 + ty*4 + i;
        if (gm >= M) continue;
        #pragma unroll
        for (int j = 0; j < 4; ++j) {
            int gn = n0 + tx*4 + j;
            if (gn >= N) continue;
            C[(size_t)gm * ldc + gn] = acc[i][j];
        }
    }
}

// ---------------------------------------------------------------------------
// combine kernels
// ---------------------------------------------------------------------------
__global__ void combine_add2(const float* __restrict__ p0, float* __restrict__ o,
                             long stride) {
    int i = blockIdx.x * 256 + threadIdx.x;   // float4 elements
    float4 x = ((const float4*)p0)[i];
    float4 y = ((const float4*)(p0 + stride))[i];
    float4 r; r.x=x.x+y.x; r.y=x.y+y.y; r.z=x.z+y.z; r.w=x.w+y.w;
    ((float4*)o)[i] = r;
}

__global__ void combine_solm4(const float* __restrict__ p, float* __restrict__ o) {
    int i = blockIdx.x * 256 + threadIdx.x;   // 73728 elems -> 288 WGs
    o[i] = p[i] + p[i + 73728] + p[i + 2*73728] + p[i + 3*73728];
}

// symmetric combine: partials valid only for m>=n; prior symmetric; write both
__global__ void combine_prior4_sym(const float* __restrict__ p0,
                                   const float* __restrict__ xin,
                                   const float* __restrict__ W2g,
                                   float* __restrict__ o, long stride) {
    __shared__ float w[16];
    int tid = threadIdx.x;
    if (tid < 16) w[tid] = W2g[tid];
    __syncthreads();
    int idx = blockIdx.x * 256 + tid;           // over 4*N2
    int b = idx / N2;
    int rem = idx - b * N2;
    int m = rem / NPTS, n = rem - m * NPTS;
    if (m < n) return;
    const float* xb = xin + (size_t)b * NPTS * 2;
    float r0 = xb[m*2+0] - xb[n*2+0];
    float r1 = xb[m*2+1] - xb[n*2+1];
    float u = (r0*r0 + r1*r1) * INVL2;
    float Kv = expf(-0.5f * u);
    float i2 = INVL2 * INVL2;
    float gK0 = r0 * INVL2 * Kv;
    float gK1 = r1 * INVL2 * Kv;
    float lapK = (u - 2.0f) * INVL2 * Kv;
    float gg00 = (INVL2 - r0*r0*i2) * Kv;
    float gg01 = (-r0*r1*i2) * Kv;
    float gg11 = (INVL2 - r1*r1*i2) * Kv;
    float gl0 = r0 * i2 * (4.0f - u) * Kv;
    float gl1 = r1 * i2 * (4.0f - u) * Kv;
    float ll = ((u-2.0f)*(u-2.0f) - 4.0f*u + 4.0f) * i2 * Kv;
    float prior =
          w[0]*Kv + w[1]*gK0 + w[2]*gK1 + w[3]*lapK
        + w[4]*(-gK0) + w[5]*gg00 + w[6]*gg01 + w[7]*gl0
        + w[8]*(-gK1) + w[9]*gg01 + w[10]*gg11 + w[11]*gl1
        + w[12]*lapK + w[13]*(-gl0) + w[14]*(-gl1) + w[15]*ll;
    float v = p0[idx] + p0[idx + stride] + p0[idx + 2*stride] + p0[idx + 3*stride]
            + prior;
    if (m == n) v += 1.1e-4f;
    o[(size_t)b * N2 + (size_t)m * NPTS + n] = v;
    if (m != n)
        o[(size_t)b * N2 + (size_t)n * NPTS + m] = v;
}

// ---------------------------------------------------------------------------
// opiKW2[b][i] = sum_j W2[i][j] * opiK[b][j]  — safe in-place (per-element)
// ---------------------------------------------------------------------------
__global__ void opiw2_k(const float* __restrict__ opiK, const float* __restrict__ W2,
                        float* __restrict__ outB) {
    int idx = blockIdx.x * 256 + threadIdx.x;
    int b = idx / N2;
    int rem = idx - b * N2;
    size_t base = (size_t)b * 4 * N2 + rem;
    float k0 = opiK[base], k1 = opiK[base + N2], k2 = opiK[base + 2*N2], k3 = opiK[base + 3*N2];
    #pragma unroll
    for (int i = 0; i < 4; ++i)
        outB[base + (size_t)i * N2] = W2[i*4+0]*k0 + W2[i*4+1]*k1 + W2[i*4+2]*k2 + W2[i*4+3]*k3;
}

// ---------------------------------------------------------------------------
__global__ __launch_bounds__(256)
void amean_k(const float* __restrict__ opimean, const float* __restrict__ weight,
             const float* __restrict__ bias, float* __restrict__ out) {
    int b = blockIdx.y;
    int m0 = blockIdx.x * 32;
    __shared__ float Wl[64][128];
    __shared__ float om[32][128];
    int tid = threadIdx.x;
    for (int idx = tid; idx < 64*128; idx += 256) Wl[idx / 128][idx & 127] = weight[idx];
    for (int idx = tid; idx < 32*128; idx += 256) {
        int m = idx >> 7, ck = idx & 127, c = ck >> 2, kop = ck & 3;
        om[m][ck] = opimean[((size_t)b * 4 + kop) * NPTS * 32 + (size_t)(m0 + m) * 32 + c];
    }
    __syncthreads();
    int ml = tid >> 3, o0 = (tid & 7) * 8;
    float acc[8] = {};
    for (int ck = 0; ck < 128; ++ck) {
        float v = om[ml][ck];
        #pragma unroll
        for (int q = 0; q < 8; ++q) acc[q] += v * Wl[o0+q][ck];
    }
    #pragma unroll
    for (int q = 0; q < 8; ++q)
        out[4608 + ((size_t)b * NPTS + m0 + ml) * 64 + o0 + q] = acc[q] + bias[o0+q];
}

// ---------------------------------------------------------------------------
static inline int gridSwz(int MT, int Z) { return 8 * 9 * ((MT * Z + 7) / 8); }

extern "C" void kernel_launch(void* const* d_in, const int* in_sizes, int n_in,
                              void* d_out, int out_size, void* d_ws, size_t ws_size,
                              hipStream_t stream) {
    const float* xin    = (const float*)d_in[0];
    const float* meanin = (const float*)d_in[1];
    const float* Kin    = (const float*)d_in[2];
    const float* weight = (const float*)d_in[3];
    const float* bias   = (const float*)d_in[4];
    float* out = (float*)d_out;
    float* ws  = (float*)d_ws;

    const long N2L = N2;
    float* W2      = ws;                       // 16 (pad 64)
    float* LinvKK  = ws + 64;                  // 4*9*4096
    float* R1 = LinvKK + 147456;               // 4*N2: Kxx/A; later iW (Kin@Kinv)
    float* R2 = R1 + 4*N2L;                    // 4*N2: Linv; later solm/opim
    float* R3 = R2 + 4*N2L;                    // 4*N2: L panels; later Kinv
    float* R4 = R3 + 4*N2L;                    // 16*N2: opiK; later opiKW2 (in-place)
    float* R5 = R4 + 16*N2L;                   // 16*N2: Kinv partials; KiO(+sp0); final partials
    float* R6 = R5 + 16*N2L;                   // 16*N2: solm/iW partials; KiO sp1; H'

    // zero Linv (upper triangle must be 0)
    hipMemsetAsync(R2, 0, (size_t)4 * N2 * sizeof(float), stream);
    copy_xout<<<dim3(18), dim3(256), 0, stream>>>(xin, out);
    build_k<<<dim3((BSZ*N2)/256), dim3(256), 0, stream>>>(xin, R1, R4);
    w2_k<<<dim3(1), dim3(256), 0, stream>>>(weight, W2);
    // Cholesky: 9 launches. L panels -> R3; diag inverses -> LinvKK
    chol_diag0<<<dim3(BSZ), dim3(256), 0, stream>>>(R1, LinvKK);
    for (int kb = 0; kb < NT - 1; ++kb) {
        int t = NT - 1 - kb;
        chol_step<<<dim3(t*(t+1)/2, BSZ), dim3(256), 0, stream>>>(R1, R3, LinvKK, kb);
    }
    // triangular inverse -> R2
    trinv_blk<<<dim3(4, NT, BSZ), dim3(256), 0, stream>>>(R3, LinvKK, R2);
    // Kinv = Linv^T @ Linv  (SK2+tri, swizzled; partials -> R5; combine -> R3)
    mm_kernel<1,0,2,1,1,0,0><<<dim3(gridSwz(9,8)), dim3(256), 0, stream>>>(
        R2, R2, R5, 576,576,576,576, 576,576,576,
        N2L,N2L,N2L, 0,0, 4*N2L, 9);
    combine_add2<<<dim3(1296), dim3(256), 0, stream>>>(R5, R3, 4*N2L);
    // sol_mean = Kinv @ meanin  (SK4 partials -> R6; combine -> R2)
    mm_kernel<0,0,4,0,0,0,0><<<dim3(1,9,16), dim3(256), 0, stream>>>(
        R3, meanin, R6, 576,32,576,576, 576,32,32,
        N2L,18432,18432, 0,0, 73728, 9);
    combine_solm4<<<dim3(288), dim3(256), 0, stream>>>(R6, R2);
    // opimean = opiK @ sol_mean -> R2+73728
    mm_kernel<0,0,1,0,0,0,0><<<dim3(1,36,BSZ), dim3(256), 0, stream>>>(
        R4, R2, R2 + 73728, 2304,32,576,576, 576,32,32,
        4*N2L,18432,73728, 0,0, 0, 9);
    amean_k<<<dim3(18,BSZ), dim3(256), 0, stream>>>(R2 + 73728, weight, bias, out);
    // iW = Kin @ Kinv  (SK2, swizzled; partials -> R6; combine -> R1)
    mm_kernel<0,0,2,0,1,0,0><<<dim3(gridSwz(9,8)), dim3(256), 0, stream>>>(
        Kin, R3, R6, 576,576,576,576, 576,576,576,
        N2L,N2L,N2L, 0,0, 4*N2L, 9);
    combine_add2<<<dim3(1296), dim3(256), 0, stream>>>(R6, R1, 4*N2L);
    // KiO = opiK @ Kinv  (plane-pair, SK2: sp0->R5, sp1->R6; combine -> R5)
    mm_p2<2,0><<<dim3(gridSwz(18,8)), dim3(256), 0, stream>>>(
        R4, R3, R5, 4*N2L, N2L, 4*N2L, 16*N2L);
    combine_add2<<<dim3(5184), dim3(256), 0, stream>>>(R5, R5, 16*N2L);
    // opiKW2 in-place on R4 (opiK no longer needed)
    opiw2_k<<<dim3((BSZ*N2)/256), dim3(256), 0, stream>>>(R4, W2, R4);
    // H' = KiO @ (iW - I)  (plane-pair, SK1, -I fold) -> R6
    mm_p2<1,1><<<dim3(gridSwz(18,4)), dim3(256), 0, stream>>>(
        R5, R1, R6, 4*N2L, N2L, 4*N2L, 0);
    // final AKA partial GEMM — SYMMETRIC: only 45 lower tiles (my>=nx), SK4.
    // partials -> R5 (sC=N2 batch plane, sSplit=4*N2 split plane)
    mm_kernel<0,1,4,0,0,0,1><<<dim3(45,1,BSZ*4), dim3(256), 0, stream>>>(
        R6, R4, R5, 576,576,2304,576, 576,576,576,
        4*N2L, 4*N2L, N2L, N2L,N2L, 4*N2L, 9);
    // output 2: combine 4 partials (m>=n) + analytic prior + jitter, mirrored
    combine_prior4_sym<<<dim3(5184), dim3(256), 0, stream>>>(
        R5, xin, W2, out + 152064, 4*N2L);
}